// Round 11
// baseline (813.232 us; speedup 1.0000x reference)
//
#include <hip/hip_runtime.h>
#include <hip/hip_bf16.h>
#include <math.h>

// Problem constants (B=32, T=256, V=32000, D=512)
#define R   8192    // B*T rows
#define TT  256
#define D   512
#define V   32000
#define G3  1536    // 3*D (z|f|o)

typedef __attribute__((ext_vector_type(8))) short bf16x8;
typedef __attribute__((ext_vector_type(4))) float f32x4;
typedef __attribute__((ext_vector_type(4))) int   i32x4;
typedef __attribute__((ext_vector_type(8))) int   i32x8;

__device__ __forceinline__ float bf2f(ushort u) {
  union { unsigned int i; float f; } x; x.i = ((unsigned int)u) << 16; return x.f;
}
__device__ __forceinline__ ushort f2bf(float f) {   // RNE
  union { float f; unsigned int i; } x; x.f = f;
  unsigned int r = x.i + 0x7fffu + ((x.i >> 16) & 1u);
  return (ushort)(r >> 16);
}

// f32 -> OCP e4m3fn, round-nearest-even, clamp to 448. Exact integer-grid method.
__device__ __forceinline__ unsigned char f2e4m3(float f) {
  unsigned char s = (__float_as_uint(f) >> 31) ? 0x80 : 0x00;
  float a = fabsf(f);
  if (!(a < 448.f)) return s | 0x7e;       // clamp (no NaN/overflow in our data)
  if (a == 0.f) return s;
  int ef; frexpf(a, &ef);                  // a = m*2^ef, m in [0.5,1)
  int E = ef - 1;                          // a = (2m)*2^E
  if (E < -6) E = -6;                      // denormal grid
  float ulp = ldexpf(1.f, E - 3);
  int qi = (int)rintf(a / ulp);            // exact scale (pow2), RNE, qi in [0,16]
  if (qi >= 16) { E += 1; qi = 8; }
  unsigned char bits = (qi < 8) ? (unsigned char)qi
                                : (unsigned char)(((E + 7) << 3) | (qi - 8));
  return s | bits;
}

// phys-K transpose within each 128-elem block: element k stored at
// poff(k) = (k&~127) | h*32 | ks*8 | j  where k = (k&~127)+ks*32+h*8+j.
// Lane h's 4x8B K-slices (ks=0..3) land contiguous 32B -> the exact v8i32
// operand of the K=128 scaled MFMA.
__device__ __forceinline__ int physk(int d) {
  return (d & ~127) | (((d >> 3) & 3) << 5) | (((d >> 5) & 3) << 3) | (d & 7);
}

__device__ __forceinline__ void gload16(const void* g, void* l) {
  __builtin_amdgcn_global_load_lds((const __attribute__((address_space(1))) void*)g,
                                   (__attribute__((address_space(3))) void*)l, 16, 0, 0);
}

// ---------------- embedding gather -> XA8 fp8 phys-K [R][1024] = [x_prev | x] ----------------
__global__ __launch_bounds__(256) void embed_kernel(const int* __restrict__ tok,
                                                    const float4* __restrict__ emb,
                                                    unsigned char* __restrict__ XA8) {
  int idx = blockIdx.x * 256 + threadIdx.x;   // over R*128 float4s
  int r = idx >> 7, d4 = idx & 127;
  float4 v = emb[(size_t)tok[r] * 128 + d4];
  uchar4 h8;
  h8.x = f2e4m3(v.x); h8.y = f2e4m3(v.y); h8.z = f2e4m3(v.z); h8.w = f2e4m3(v.w);
  int pp = physk(d4 * 4);                     // aligned-4 contiguous run
  *(uchar4*)(XA8 + (size_t)r * 1024 + 512 + pp) = h8;          // x part
  int t = r & (TT - 1);
  if (t < TT - 1) *(uchar4*)(XA8 + (size_t)(r + 1) * 1024 + pp) = h8;  // next row x_prev
  if (t == 0) { uchar4 z = {0, 0, 0, 0}; *(uchar4*)(XA8 + (size_t)r * 1024 + pp) = z; }
}

// ---------------- coalesced fp8 phys-K transpose-convert helper ----------------
// tile[64][65] holds [k][n] f32 for k in [k0,k0+64), n in [n0,n0+64).
// phys-K image of this 64-k half-block within each output row = 4 runs of 16B
// at (k0&~127) + h*32 + ((k0&64)?16:0), byte ksl*8+j <- element ksl*32+h*8+j.
// 256 threads: (nn = t&63, h = t>>6) each emit one 16B store.
__device__ __forceinline__ void tconv_write(const float (*tile)[65],
                                            unsigned char* __restrict__ dstrow0,
                                            size_t ldb, int k0, int t) {
  int nn = t & 63, h = t >> 6;
  union { unsigned char c[16]; uint4 q; } u;
#pragma unroll
  for (int ksl = 0; ksl < 2; ++ksl)
#pragma unroll
    for (int j = 0; j < 8; ++j)
      u.c[ksl * 8 + j] = f2e4m3(tile[ksl * 32 + h * 8 + j][nn]);
  unsigned char* dst = dstrow0 + (size_t)nn * ldb + (k0 & ~127) + h * 32 + ((k0 & 64) ? 16 : 0);
  *(uint4*)dst = u.q;
}

// ---------------- weight transpose+convert: WT8[1536][1024] fp8 phys-K ----------------
// WT8[g*512+e][physk(i*512+d)] = Wg[i][d][e]
__global__ __launch_bounds__(256) void wconv(const float* __restrict__ Wz,
                                             const float* __restrict__ Wf,
                                             const float* __restrict__ Wo,
                                             unsigned char* __restrict__ WT8) {
  __shared__ float tile[64][65];
  int z = blockIdx.z, g = z >> 1, i = z & 1;
  const float* src = (g == 0) ? Wz : (g == 1 ? Wf : Wo);
  src += (size_t)i * D * D;
  int d0 = blockIdx.x * 64, e0 = blockIdx.y * 64;
  int t = threadIdx.x, c = t & 63, rq = t >> 6;
#pragma unroll
  for (int p = 0; p < 16; ++p) {
    int dd = p * 4 + rq;
    tile[dd][c] = src[(size_t)(d0 + dd) * D + e0 + c];   // [k=d][n=e]
  }
  __syncthreads();
  tconv_write(tile, WT8 + (size_t)(g * D + e0) * 1024, 1024, i * 512 + d0, t);
}

// ---------------- softmax weight transpose+convert: SW8T[32000][512] fp8 phys-K ----------------
__global__ __launch_bounds__(256) void swconv(const float* __restrict__ SW,
                                              unsigned char* __restrict__ SWT) {
  __shared__ float tile[64][65];
  int k0 = blockIdx.x * 64, n0 = blockIdx.y * 64;
  int t = threadIdx.x, c = t & 63, rq = t >> 6;
#pragma unroll
  for (int p = 0; p < 16; ++p) {
    int kk = p * 4 + rq;
    tile[kk][c] = SW[(size_t)(k0 + kk) * V + n0 + c];
  }
  __syncthreads();
  tconv_write(tile, SWT + (size_t)n0 * 512, 512, k0, t);
}

// ---------------- bias concat ----------------
__global__ void bcat_kernel(const float* bz0, const float* bf0, const float* bo0,
                            const float* bz1, const float* bf1, const float* bo1,
                            float* BC0, float* BC1) {
  int idx = blockIdx.x * 256 + threadIdx.x;
  if (idx >= 2 * G3) return;
  int layer = idx / G3, rem = idx % G3, g = rem >> 9, e = rem & 511;
  const float* s = (layer == 0) ? (g == 0 ? bz0 : (g == 1 ? bf0 : bo0))
                                : (g == 0 ? bz1 : (g == 1 ? bf1 : bo1));
  (layer == 0 ? BC0 : BC1)[rem] = s[e];
}

// ---------------- shared MX-fp8 128x128 GEMM core (LDS-staged; used by gemm_pre) ----------------
// 256 thr / 4 waves (wm,wn in 2x2 of 64x64), BK=128, 32KB LDS single-buffered.
// Operands SWAPPED in the MFMA (mfma(b8, a8)): C row = lane&15 (lane-local),
// C col = (lane>>4)*4 + j. Row = 128B = 8 slots of 16B; LDS slot s of row r
// holds source slot s^(r&7) (pre-swizzled global source, rule #21); frag reads
// at slots (hi*2+q)^(r&7).
template<int LD, int NKT>
__device__ __forceinline__ void mx_core(const unsigned char* __restrict__ A,
                                        const unsigned char* __restrict__ B,
                                        int row0, int col0, char* lds,
                                        f32x4 acc[4][4]) {
  char* As = lds;
  char* Bs = lds + 16384;
  const int t = threadIdx.x, lane = t & 63, w = t >> 6;
  const int wm = w >> 1, wn = w & 1;
  const int lo = lane & 15, hi = lane >> 4;
  const int gr = t >> 3;             // row within 32-row issue
  const int ss = (t & 7) ^ (gr & 7); // inverse-swizzled source slot
  const int x  = lo & 7;             // frag-read row swizzle

#pragma unroll 1
  for (int kt = 0; kt < NKT; ++kt) {
    const int k0 = kt * 128;
#pragma unroll
    for (int i = 0; i < 4; ++i) {
      gload16(A + (size_t)(row0 + i * 32 + gr) * LD + k0 + ss * 16,
              As + i * 4096 + t * 16);
      gload16(B + (size_t)(col0 + i * 32 + gr) * LD + k0 + ss * 16,
              Bs + i * 4096 + t * 16);
    }
    __syncthreads();
    i32x8 b8[4];
#pragma unroll
    for (int ni = 0; ni < 4; ++ni) {
      const char* rb = Bs + (wn * 64 + ni * 16 + lo) * 128;
      union { i32x8 v8; i32x4 v4[2]; } u;
      u.v4[0] = *(const i32x4*)(rb + ((hi * 2 + 0) ^ x) * 16);
      u.v4[1] = *(const i32x4*)(rb + ((hi * 2 + 1) ^ x) * 16);
      b8[ni] = u.v8;
    }
#pragma unroll
    for (int mi = 0; mi < 4; ++mi) {
      const char* rb = As + (wm * 64 + mi * 16 + lo) * 128;
      union { i32x8 v8; i32x4 v4[2]; } u;
      u.v4[0] = *(const i32x4*)(rb + ((hi * 2 + 0) ^ x) * 16);
      u.v4[1] = *(const i32x4*)(rb + ((hi * 2 + 1) ^ x) * 16);
      i32x8 a8 = u.v8;
#pragma unroll
      for (int ni = 0; ni < 4; ++ni)
        acc[mi][ni] = __builtin_amdgcn_mfma_scale_f32_16x16x128_f8f6f4(
            b8[ni], a8, acc[mi][ni], 0, 0, 0, 0x7F, 0, 0x7F);
    }
    __syncthreads();
  }
}

// ---------------- QRNN pre-activation GEMM (8192x1536x1024, MX-fp8) ----------------
__global__ __launch_bounds__(256, 2) void gemm_pre_fp8(const unsigned char* __restrict__ A,
                                                       const unsigned char* __restrict__ B,
                                                       const float* __restrict__ bcat,
                                                       ushort* __restrict__ PRE) {
  __shared__ char lds[32768];
  const int t = threadIdx.x, lane = t & 63, w = t >> 6;
  const int wm = w >> 1, wn = w & 1;
  const int lo = lane & 15, hi = lane >> 4;
  const int row0 = blockIdx.x * 128, col0 = blockIdx.y * 128;

  f32x4 acc[4][4];
#pragma unroll
  for (int i = 0; i < 4; ++i)
#pragma unroll
    for (int j = 0; j < 4; ++j) { f32x4 z = {0.f,0.f,0.f,0.f}; acc[i][j] = z; }

  mx_core<1024, 8>(A, B, row0, col0, lds, acc);

  // swapped layout: row = +lo (lane-local), col = colb + j -> ushort4 stores
#pragma unroll
  for (int mi = 0; mi < 4; ++mi) {
    const int row = row0 + wm * 64 + mi * 16 + lo;
#pragma unroll
    for (int ni = 0; ni < 4; ++ni) {
      const int colb = col0 + wn * 64 + ni * 16 + hi * 4;
      ushort4 v;
      v.x = f2bf(acc[mi][ni][0] + bcat[colb + 0]);
      v.y = f2bf(acc[mi][ni][1] + bcat[colb + 1]);
      v.z = f2bf(acc[mi][ni][2] + bcat[colb + 2]);
      v.w = f2bf(acc[mi][ni][3] + bcat[colb + 3]);
      *(ushort4*)(PRE + (size_t)row * G3 + colb) = v;
    }
  }
}

// ---------------- MX-fp8 logits GEMM (8192x32000x512) + fused exp-sum + target ----------------
// v6: BARRIER-FREE direct-streaming. No LDS: each lane loads its phys-K 32B
// operand slices straight from global (2x dwordx4 at k0 + hi*32 {+16}); A (4MB)
// and the active B panel (64KB, shared by 64 consecutive row-blocks) are
// L2-resident; intra-block 2x reuse is captured by L1 (16KB/kt wave working
// set). Zero __syncthreads -> no stage/drain serialization; pure TLP hiding.
// Math identical to the verified r9/r10 core (swizzle removed from BOTH sides).
__global__ __launch_bounds__(256) void gemm_lse_fp8(const unsigned char* __restrict__ A,
                                                    const unsigned char* __restrict__ B,
                                                    const float* __restrict__ SB,
                                                    const int* __restrict__ tgt,
                                                    float* __restrict__ SUM,
                                                    float* __restrict__ TGL) {
  const int t = threadIdx.x, lane = t & 63, w = t >> 6;
  const int wm = w >> 1, wn = w & 1;
  const int lo = lane & 15, hi = lane >> 4;
  const int row0 = blockIdx.x * 128, col0 = blockIdx.y * 128;

  const unsigned char* ab = A + (size_t)(row0 + wm * 64 + lo) * 512 + hi * 32;
  const unsigned char* bb = B + (size_t)(col0 + wn * 64 + lo) * 512 + hi * 32;

  f32x4 acc[4][4];
#pragma unroll
  for (int i = 0; i < 4; ++i)
#pragma unroll
    for (int j = 0; j < 4; ++j) { f32x4 z = {0.f,0.f,0.f,0.f}; acc[i][j] = z; }

#pragma unroll 1
  for (int kt = 0; kt < 4; ++kt) {
    const int k0 = kt * 128;
    i32x8 b8[4];
#pragma unroll
    for (int ni = 0; ni < 4; ++ni) {
      const unsigned char* p = bb + (size_t)(ni * 16) * 512 + k0;
      union { i32x8 v8; i32x4 v4[2]; } u;
      u.v4[0] = *(const i32x4*)(p);
      u.v4[1] = *(const i32x4*)(p + 16);
      b8[ni] = u.v8;
    }
#pragma unroll
    for (int mi = 0; mi < 4; ++mi) {
      const unsigned char* p = ab + (size_t)(mi * 16) * 512 + k0;
      union { i32x8 v8; i32x4 v4[2]; } u;
      u.v4[0] = *(const i32x4*)(p);
      u.v4[1] = *(const i32x4*)(p + 16);
      i32x8 a8 = u.v8;
#pragma unroll
      for (int ni = 0; ni < 4; ++ni)
        acc[mi][ni] = __builtin_amdgcn_mfma_scale_f32_16x16x128_f8f6f4(
            b8[ni], a8, acc[mi][ni], 0, 0, 0, 0x7F, 0, 0x7F);
    }
  }

  // epilogue (swapped layout): out_row = row0+wm*64+mi*16+lo (lane-local!),
  // vocab_col = col0+wn*64+ni*16+hi*4+j. In-lane exp-sum over (ni,j);
  // 2-stage shfl over hi lanes; one atomic per row per wave.
#pragma unroll
  for (int mi = 0; mi < 4; ++mi) {
    const int row = row0 + wm * 64 + mi * 16 + lo;
    const int tg  = tgt[row];
    float s = 0.f;
#pragma unroll
    for (int ni = 0; ni < 4; ++ni) {
      const int colb = col0 + wn * 64 + ni * 16 + hi * 4;
#pragma unroll
      for (int j = 0; j < 4; ++j) {
        float v = acc[mi][ni][j] + SB[colb + j];
        if (colb + j == tg) TGL[row] = v;    // exactly one writer per row
        s += __expf(v);
      }
    }
    s += __shfl_xor(s, 16, 64);
    s += __shfl_xor(s, 32, 64);
    if (hi == 0) atomicAdd(&SUM[row], s);
  }
}

// ---------------- fo-pool scan (bf16 in; fp8 phys-K out) ----------------
// mode 0: OUT8 = YA8 [R][1024]: [r][512+pk]=h, [r+1][pk]=h (t<255), [r][pk]=0 (t==0)
// mode 1: OUT8 = H8 [R][512]
__global__ __launch_bounds__(64) void scan_kernel(const ushort* __restrict__ PRE,
                                                  unsigned char* __restrict__ OUT8,
                                                  int mode) {
  int idx = blockIdx.x * 64 + threadIdx.x;    // 32*512
  int b = idx >> 9, d = idx & 511;
  const ushort* p = PRE + (size_t)b * TT * G3 + d;
  int poff = physk(d);
  float c = 0.f;
  for (int t0 = 0; t0 < TT; t0 += 8) {
    float pz[8], pf[8], po[8];
#pragma unroll
    for (int i = 0; i < 8; ++i) {
      const ushort* q = p + (size_t)(t0 + i) * G3;
      pz[i] = bf2f(q[0]); pf[i] = bf2f(q[512]); po[i] = bf2f(q[1024]);
    }
#pragma unroll
    for (int i = 0; i < 8; ++i) {
      float z = 2.f / (1.f + __expf(-2.f * pz[i])) - 1.f;
      float f = 1.f / (1.f + __expf(-pf[i]));
      float o = 1.f / (1.f + __expf(-po[i]));
      c = f * c + (1.f - f) * z;
      float h = o * c;
      int tt = t0 + i;
      size_t r = (size_t)b * TT + tt;
      unsigned char hb = f2e4m3(h);
      if (mode == 0) {
        OUT8[r * 1024 + 512 + poff] = hb;
        if (tt < TT - 1) OUT8[(r + 1) * 1024 + poff] = hb;
        if (tt == 0)     OUT8[r * 1024 + poff] = 0;
      } else {
        OUT8[r * 512 + poff] = hb;
      }
    }
  }
}

// ---------------- helpers ----------------
__global__ void zero_kernel(float* __restrict__ p, int n) {
  int i = blockIdx.x * 256 + threadIdx.x;
  if (i < n) p[i] = 0.f;
}

__global__ __launch_bounds__(256) void cost_kernel(const float* __restrict__ sumexp,
                                                   const float* __restrict__ tgl,
                                                   float* __restrict__ out) {
  int t = threadIdx.x;
  float s = 0.f;
  for (int r = t; r < R; r += 256) s += logf(sumexp[r]) - tgl[r];
#pragma unroll
  for (int m = 1; m < 64; m <<= 1) s += __shfl_xor(s, m, 64);
  __shared__ float red[4];
  int wave = t >> 6, lane = t & 63;
  if (lane == 0) red[wave] = s;
  __syncthreads();
  if (t == 0) out[0] = (red[0] + red[1] + red[2] + red[3]) / (float)R;
}

extern "C" void kernel_launch(void* const* d_in, const int* in_sizes, int n_in,
                              void* d_out, int out_size, void* d_ws, size_t ws_size,
                              hipStream_t stream) {
  const int*   tok = (const int*)d_in[0];
  const int*   tgt = (const int*)d_in[1];
  const float* emb = (const float*)d_in[2];
  const float* Wz0 = (const float*)d_in[3];  const float* bz0 = (const float*)d_in[4];
  const float* Wf0 = (const float*)d_in[5];  const float* bf0 = (const float*)d_in[6];
  const float* Wo0 = (const float*)d_in[7];  const float* bo0 = (const float*)d_in[8];
  const float* Wz1 = (const float*)d_in[9];  const float* bz1 = (const float*)d_in[10];
  const float* Wf1 = (const float*)d_in[11]; const float* bf1 = (const float*)d_in[12];
  const float* Wo1 = (const float*)d_in[13]; const float* bo1 = (const float*)d_in[14];
  const float* SW  = (const float*)d_in[15]; const float* SB  = (const float*)d_in[16];
  float* out = (float*)d_out;

  // workspace layout (bytes), total ~49.4 MB:
  char* base = (char*)d_ws;
  unsigned char* XA8 = (unsigned char*)(base);             //  8,388,608 [R][1024] fp8 phys-K
  unsigned char* YA8 = (unsigned char*)(base + 8388608);   //  8,388,608 [R][1024] fp8 phys-K
  ushort*        PRE = (ushort*)(base + 16777216);         // 25,165,824 [R][1536] bf16
  unsigned char* H8  = (unsigned char*)(base + 41943040);  //  4,194,304 [R][512]  fp8 phys-K
  unsigned char* WT80 = (unsigned char*)(base + 46137344); //  1,572,864 [1536][1024] fp8 phys-K
  unsigned char* WT81 = (unsigned char*)(base + 47710208); //  1,572,864
  float*         BC0 = (float*)(base + 49283072);          //  6,144
  float*         BC1 = (float*)(base + 49289216);          //  6,144
  float*         SUM = (float*)(base + 49295360);          //  32,768
  float*         TGL = (float*)(base + 49328128);          //  32,768
  unsigned char* SW8T = (unsigned char*)(base);            // 16,384,000 — aliases XA8+YA8 (dead by then)

  embed_kernel<<<R * 128 / 256, 256, 0, stream>>>(tok, (const float4*)emb, XA8);
  wconv<<<dim3(8, 8, 6), 256, 0, stream>>>(Wz0, Wf0, Wo0, WT80);
  wconv<<<dim3(8, 8, 6), 256, 0, stream>>>(Wz1, Wf1, Wo1, WT81);
  bcat_kernel<<<12, 256, 0, stream>>>(bz0, bf0, bo0, bz1, bf1, bo1, BC0, BC1);

  gemm_pre_fp8<<<dim3(64, 12), 256, 0, stream>>>(XA8, WT80, BC0, PRE);
  scan_kernel<<<256, 64, 0, stream>>>(PRE, YA8, 0);
  gemm_pre_fp8<<<dim3(64, 12), 256, 0, stream>>>(YA8, WT81, BC1, PRE);
  scan_kernel<<<256, 64, 0, stream>>>(PRE, H8, 1);

  // SW8T aliases XA8/YA8 — both dead after the second gemm_pre_fp8
  swconv<<<dim3(8, 500), 256, 0, stream>>>(SW, SW8T);
  zero_kernel<<<32, 256, 0, stream>>>(SUM, R);
  gemm_lse_fp8<<<dim3(64, 250), 256, 0, stream>>>(H8, SW8T, SB, tgt, SUM, TGL);
  cost_kernel<<<1, 256, 0, stream>>>(SUM, TGL, out);
}

// Round 12
// 470.137 us; speedup vs baseline: 1.7298x; 1.7298x over previous
//
#include <hip/hip_runtime.h>
#include <hip/hip_bf16.h>
#include <math.h>

// Problem constants (B=32, T=256, V=32000, D=512)
#define R   8192    // B*T rows
#define TT  256
#define D   512
#define V   32000
#define G3  1536    // 3*D (z|f|o)

typedef __attribute__((ext_vector_type(8))) short bf16x8;
typedef __attribute__((ext_vector_type(4))) float f32x4;
typedef __attribute__((ext_vector_type(4))) int   i32x4;
typedef __attribute__((ext_vector_type(8))) int   i32x8;

__device__ __forceinline__ float bf2f(ushort u) {
  union { unsigned int i; float f; } x; x.i = ((unsigned int)u) << 16; return x.f;
}
__device__ __forceinline__ ushort f2bf(float f) {   // RNE
  union { float f; unsigned int i; } x; x.f = f;
  unsigned int r = x.i + 0x7fffu + ((x.i >> 16) & 1u);
  return (ushort)(r >> 16);
}

// f32 -> OCP e4m3fn, round-nearest-even, clamp to 448. Exact integer-grid method.
__device__ __forceinline__ unsigned char f2e4m3(float f) {
  unsigned char s = (__float_as_uint(f) >> 31) ? 0x80 : 0x00;
  float a = fabsf(f);
  if (!(a < 448.f)) return s | 0x7e;       // clamp (no NaN/overflow in our data)
  if (a == 0.f) return s;
  int ef; frexpf(a, &ef);                  // a = m*2^ef, m in [0.5,1)
  int E = ef - 1;                          // a = (2m)*2^E
  if (E < -6) E = -6;                      // denormal grid
  float ulp = ldexpf(1.f, E - 3);
  int qi = (int)rintf(a / ulp);            // exact scale (pow2), RNE, qi in [0,16]
  if (qi >= 16) { E += 1; qi = 8; }
  unsigned char bits = (qi < 8) ? (unsigned char)qi
                                : (unsigned char)(((E + 7) << 3) | (qi - 8));
  return s | bits;
}

// phys-K transpose within each 128-elem block: element k stored at
// poff(k) = (k&~127) | h*32 | ks*8 | j  where k = (k&~127)+ks*32+h*8+j.
// Lane h's 4x8B K-slices (ks=0..3) land contiguous 32B -> the exact v8i32
// operand of the K=128 scaled MFMA.
__device__ __forceinline__ int physk(int d) {
  return (d & ~127) | (((d >> 3) & 3) << 5) | (((d >> 5) & 3) << 3) | (d & 7);
}

__device__ __forceinline__ void gload16(const void* g, void* l) {
  __builtin_amdgcn_global_load_lds((const __attribute__((address_space(1))) void*)g,
                                   (__attribute__((address_space(3))) void*)l, 16, 0, 0);
}

// ---------------- embedding gather -> XA8 fp8 phys-K [R][1024] = [x_prev | x] ----------------
__global__ __launch_bounds__(256) void embed_kernel(const int* __restrict__ tok,
                                                    const float4* __restrict__ emb,
                                                    unsigned char* __restrict__ XA8) {
  int idx = blockIdx.x * 256 + threadIdx.x;   // over R*128 float4s
  int r = idx >> 7, d4 = idx & 127;
  float4 v = emb[(size_t)tok[r] * 128 + d4];
  uchar4 h8;
  h8.x = f2e4m3(v.x); h8.y = f2e4m3(v.y); h8.z = f2e4m3(v.z); h8.w = f2e4m3(v.w);
  int pp = physk(d4 * 4);                     // aligned-4 contiguous run
  *(uchar4*)(XA8 + (size_t)r * 1024 + 512 + pp) = h8;          // x part
  int t = r & (TT - 1);
  if (t < TT - 1) *(uchar4*)(XA8 + (size_t)(r + 1) * 1024 + pp) = h8;  // next row x_prev
  if (t == 0) { uchar4 z = {0, 0, 0, 0}; *(uchar4*)(XA8 + (size_t)r * 1024 + pp) = z; }
}

// ---------------- coalesced fp8 phys-K transpose-convert helper ----------------
__device__ __forceinline__ void tconv_write(const float (*tile)[65],
                                            unsigned char* __restrict__ dstrow0,
                                            size_t ldb, int k0, int t) {
  int nn = t & 63, h = t >> 6;
  union { unsigned char c[16]; uint4 q; } u;
#pragma unroll
  for (int ksl = 0; ksl < 2; ++ksl)
#pragma unroll
    for (int j = 0; j < 8; ++j)
      u.c[ksl * 8 + j] = f2e4m3(tile[ksl * 32 + h * 8 + j][nn]);
  unsigned char* dst = dstrow0 + (size_t)nn * ldb + (k0 & ~127) + h * 32 + ((k0 & 64) ? 16 : 0);
  *(uint4*)dst = u.q;
}

// ---------------- weight transpose+convert: WT8[1536][1024] fp8 phys-K ----------------
__global__ __launch_bounds__(256) void wconv(const float* __restrict__ Wz,
                                             const float* __restrict__ Wf,
                                             const float* __restrict__ Wo,
                                             unsigned char* __restrict__ WT8) {
  __shared__ float tile[64][65];
  int z = blockIdx.z, g = z >> 1, i = z & 1;
  const float* src = (g == 0) ? Wz : (g == 1 ? Wf : Wo);
  src += (size_t)i * D * D;
  int d0 = blockIdx.x * 64, e0 = blockIdx.y * 64;
  int t = threadIdx.x, c = t & 63, rq = t >> 6;
#pragma unroll
  for (int p = 0; p < 16; ++p) {
    int dd = p * 4 + rq;
    tile[dd][c] = src[(size_t)(d0 + dd) * D + e0 + c];   // [k=d][n=e]
  }
  __syncthreads();
  tconv_write(tile, WT8 + (size_t)(g * D + e0) * 1024, 1024, i * 512 + d0, t);
}

// ---------------- softmax weight transpose+convert: SW8T[32000][512] fp8 phys-K ----------------
__global__ __launch_bounds__(256) void swconv(const float* __restrict__ SW,
                                              unsigned char* __restrict__ SWT) {
  __shared__ float tile[64][65];
  int k0 = blockIdx.x * 64, n0 = blockIdx.y * 64;
  int t = threadIdx.x, c = t & 63, rq = t >> 6;
#pragma unroll
  for (int p = 0; p < 16; ++p) {
    int kk = p * 4 + rq;
    tile[kk][c] = SW[(size_t)(k0 + kk) * V + n0 + c];
  }
  __syncthreads();
  tconv_write(tile, SWT + (size_t)n0 * 512, 512, k0, t);
}

// ---------------- bias concat ----------------
__global__ void bcat_kernel(const float* bz0, const float* bf0, const float* bo0,
                            const float* bz1, const float* bf1, const float* bo1,
                            float* BC0, float* BC1) {
  int idx = blockIdx.x * 256 + threadIdx.x;
  if (idx >= 2 * G3) return;
  int layer = idx / G3, rem = idx % G3, g = rem >> 9, e = rem & 511;
  const float* s = (layer == 0) ? (g == 0 ? bz0 : (g == 1 ? bf0 : bo0))
                                : (g == 0 ? bz1 : (g == 1 ? bf1 : bo1));
  (layer == 0 ? BC0 : BC1)[rem] = s[e];
}

// ---------------- shared MX-fp8 128x128 GEMM core (single-buffer; lse) ----------------
// VERIFIED r9/r10. 256 thr / 4 waves (2x2 of 64x64), BK=128, 32KB LDS.
// Swapped MFMA (mfma(b8,a8)): C row = lane&15 (lane-local), C col = (lane>>4)*4+j.
template<int LD, int NKT>
__device__ __forceinline__ void mx_core(const unsigned char* __restrict__ A,
                                        const unsigned char* __restrict__ B,
                                        int row0, int col0, char* lds,
                                        f32x4 acc[4][4]) {
  char* As = lds;
  char* Bs = lds + 16384;
  const int t = threadIdx.x, lane = t & 63, w = t >> 6;
  const int wm = w >> 1, wn = w & 1;
  const int lo = lane & 15, hi = lane >> 4;
  const int gr = t >> 3;             // row within 32-row issue
  const int ss = (t & 7) ^ (gr & 7); // inverse-swizzled source slot
  const int x  = lo & 7;             // frag-read row swizzle

#pragma unroll 1
  for (int kt = 0; kt < NKT; ++kt) {
    const int k0 = kt * 128;
#pragma unroll
    for (int i = 0; i < 4; ++i) {
      gload16(A + (size_t)(row0 + i * 32 + gr) * LD + k0 + ss * 16,
              As + i * 4096 + t * 16);
      gload16(B + (size_t)(col0 + i * 32 + gr) * LD + k0 + ss * 16,
              Bs + i * 4096 + t * 16);
    }
    __syncthreads();
    i32x8 b8[4];
#pragma unroll
    for (int ni = 0; ni < 4; ++ni) {
      const char* rb = Bs + (wn * 64 + ni * 16 + lo) * 128;
      union { i32x8 v8; i32x4 v4[2]; } u;
      u.v4[0] = *(const i32x4*)(rb + ((hi * 2 + 0) ^ x) * 16);
      u.v4[1] = *(const i32x4*)(rb + ((hi * 2 + 1) ^ x) * 16);
      b8[ni] = u.v8;
    }
#pragma unroll
    for (int mi = 0; mi < 4; ++mi) {
      const char* rb = As + (wm * 64 + mi * 16 + lo) * 128;
      union { i32x8 v8; i32x4 v4[2]; } u;
      u.v4[0] = *(const i32x4*)(rb + ((hi * 2 + 0) ^ x) * 16);
      u.v4[1] = *(const i32x4*)(rb + ((hi * 2 + 1) ^ x) * 16);
      i32x8 a8 = u.v8;
#pragma unroll
      for (int ni = 0; ni < 4; ++ni)
        acc[mi][ni] = __builtin_amdgcn_mfma_scale_f32_16x16x128_f8f6f4(
            b8[ni], a8, acc[mi][ni], 0, 0, 0, 0x7F, 0, 0x7F);
    }
    __syncthreads();
  }
}

// ---------------- double-buffered counted-vmcnt MX core (T4 experiment; gemm_pre) ----------------
// Same frag math as mx_core; raw s_barrier + s_waitcnt vmcnt(8): next tile's
// 8 gloads/thread stay in flight across the barrier (never drain to 0 mid-loop).
// WAR safety: trailing s_barrier — waves pass only after lgkmcnt-gated MFMA
// issues, so all reads of the buffer being overwritten next iter completed.
template<int LD, int NKT>
__device__ __forceinline__ void mx_core_db(const unsigned char* __restrict__ A,
                                           const unsigned char* __restrict__ B,
                                           int row0, int col0, char* lds,
                                           f32x4 acc[4][4]) {
  const int t = threadIdx.x, lane = t & 63, w = t >> 6;
  const int wm = w >> 1, wn = w & 1;
  const int lo = lane & 15, hi = lane >> 4;
  const int gr = t >> 3;
  const int ss = (t & 7) ^ (gr & 7);
  const int x  = lo & 7;

  // prologue: stage tile 0 into buffer 0
#pragma unroll
  for (int i = 0; i < 4; ++i) {
    gload16(A + (size_t)(row0 + i * 32 + gr) * LD + ss * 16, lds + i * 4096 + t * 16);
    gload16(B + (size_t)(col0 + i * 32 + gr) * LD + ss * 16, lds + 16384 + i * 4096 + t * 16);
  }

#pragma unroll 1
  for (int kt = 0; kt < NKT; ++kt) {
    char* cbuf = lds + (kt & 1) * 32768;
    char* nbuf = lds + ((kt + 1) & 1) * 32768;
    if (kt + 1 < NKT) {
      const int kn = (kt + 1) * 128;
#pragma unroll
      for (int i = 0; i < 4; ++i) {
        gload16(A + (size_t)(row0 + i * 32 + gr) * LD + kn + ss * 16,
                nbuf + i * 4096 + t * 16);
        gload16(B + (size_t)(col0 + i * 32 + gr) * LD + kn + ss * 16,
                nbuf + 16384 + i * 4096 + t * 16);
      }
      asm volatile("s_waitcnt vmcnt(8)" ::: "memory");   // cur tile's 8 landed
    } else {
      asm volatile("s_waitcnt vmcnt(0)" ::: "memory");
    }
    __builtin_amdgcn_sched_barrier(0);
    asm volatile("s_barrier" ::: "memory");              // all waves' cur loads landed

    const char* As = cbuf;
    const char* Bs = cbuf + 16384;
    i32x8 b8[4];
#pragma unroll
    for (int ni = 0; ni < 4; ++ni) {
      const char* rb = Bs + (wn * 64 + ni * 16 + lo) * 128;
      union { i32x8 v8; i32x4 v4[2]; } u;
      u.v4[0] = *(const i32x4*)(rb + ((hi * 2 + 0) ^ x) * 16);
      u.v4[1] = *(const i32x4*)(rb + ((hi * 2 + 1) ^ x) * 16);
      b8[ni] = u.v8;
    }
#pragma unroll
    for (int mi = 0; mi < 4; ++mi) {
      const char* rb = As + (wm * 64 + mi * 16 + lo) * 128;
      union { i32x8 v8; i32x4 v4[2]; } u;
      u.v4[0] = *(const i32x4*)(rb + ((hi * 2 + 0) ^ x) * 16);
      u.v4[1] = *(const i32x4*)(rb + ((hi * 2 + 1) ^ x) * 16);
      i32x8 a8 = u.v8;
#pragma unroll
      for (int ni = 0; ni < 4; ++ni)
        acc[mi][ni] = __builtin_amdgcn_mfma_scale_f32_16x16x128_f8f6f4(
            b8[ni], a8, acc[mi][ni], 0, 0, 0, 0x7F, 0, 0x7F);
    }
    __builtin_amdgcn_sched_barrier(0);
    asm volatile("s_barrier" ::: "memory");              // reads done before overwrite
  }
}

// ---------------- QRNN pre-activation GEMM (8192x1536x1024, MX-fp8, dbuf) ----------------
__global__ __launch_bounds__(256, 2) void gemm_pre_fp8(const unsigned char* __restrict__ A,
                                                       const unsigned char* __restrict__ B,
                                                       const float* __restrict__ bcat,
                                                       ushort* __restrict__ PRE) {
  __shared__ char lds[65536];
  const int t = threadIdx.x, lane = t & 63, w = t >> 6;
  const int wm = w >> 1, wn = w & 1;
  const int lo = lane & 15, hi = lane >> 4;
  const int row0 = blockIdx.x * 128, col0 = blockIdx.y * 128;

  f32x4 acc[4][4];
#pragma unroll
  for (int i = 0; i < 4; ++i)
#pragma unroll
    for (int j = 0; j < 4; ++j) { f32x4 z = {0.f,0.f,0.f,0.f}; acc[i][j] = z; }

  mx_core_db<1024, 8>(A, B, row0, col0, lds, acc);

  // swapped layout: row = +lo (lane-local), col = colb + j -> ushort4 stores
#pragma unroll
  for (int mi = 0; mi < 4; ++mi) {
    const int row = row0 + wm * 64 + mi * 16 + lo;
#pragma unroll
    for (int ni = 0; ni < 4; ++ni) {
      const int colb = col0 + wn * 64 + ni * 16 + hi * 4;
      ushort4 v;
      v.x = f2bf(acc[mi][ni][0] + bcat[colb + 0]);
      v.y = f2bf(acc[mi][ni][1] + bcat[colb + 1]);
      v.z = f2bf(acc[mi][ni][2] + bcat[colb + 2]);
      v.w = f2bf(acc[mi][ni][3] + bcat[colb + 3]);
      *(ushort4*)(PRE + (size_t)row * G3 + colb) = v;
    }
  }
}

// ---------------- MX-fp8 logits GEMM (EXACT r10 revert) ----------------
__global__ __launch_bounds__(256, 2) void gemm_lse_fp8(const unsigned char* __restrict__ A,
                                                       const unsigned char* __restrict__ B,
                                                       const float* __restrict__ SB,
                                                       const int* __restrict__ tgt,
                                                       float* __restrict__ SUM,
                                                       float* __restrict__ TGL) {
  __shared__ char lds[32768];
  const int t = threadIdx.x, lane = t & 63, w = t >> 6;
  const int wm = w >> 1, wn = w & 1;
  const int lo = lane & 15, hi = lane >> 4;
  const int row0 = blockIdx.x * 128, col0 = blockIdx.y * 128;

  f32x4 acc[4][4];
#pragma unroll
  for (int i = 0; i < 4; ++i)
#pragma unroll
    for (int j = 0; j < 4; ++j) { f32x4 z = {0.f,0.f,0.f,0.f}; acc[i][j] = z; }

  mx_core<512, 4>(A, B, row0, col0, lds, acc);

  // epilogue (swapped layout): out_row = row0+wm*64+mi*16+lo (lane-local!),
  // vocab_col = col0+wn*64+ni*16+hi*4+j. In-lane exp-sum over (ni,j);
  // 2-stage shfl over hi lanes; one atomic per row per wave.
#pragma unroll
  for (int mi = 0; mi < 4; ++mi) {
    const int row = row0 + wm * 64 + mi * 16 + lo;
    const int tg  = tgt[row];
    float s = 0.f;
#pragma unroll
    for (int ni = 0; ni < 4; ++ni) {
      const int colb = col0 + wn * 64 + ni * 16 + hi * 4;
#pragma unroll
      for (int j = 0; j < 4; ++j) {
        float v = acc[mi][ni][j] + SB[colb + j];
        if (colb + j == tg) TGL[row] = v;    // exactly one writer per row
        s += __expf(v);
      }
    }
    s += __shfl_xor(s, 16, 64);
    s += __shfl_xor(s, 32, 64);
    if (hi == 0) atomicAdd(&SUM[row], s);
  }
}

// ---------------- fo-pool scan (software-pipelined; bf16 in, fp8 phys-K out) ----------------
__device__ __forceinline__ void scan_load(const ushort* __restrict__ p, int tbase,
                                          ushort* zb, ushort* fb, ushort* ob) {
#pragma unroll
  for (int i = 0; i < 8; ++i) {
    const ushort* q = p + (size_t)(tbase + i) * G3;
    zb[i] = q[0]; fb[i] = q[512]; ob[i] = q[1024];
  }
}

__device__ __forceinline__ void scan_chunk(const ushort* zb, const ushort* fb, const ushort* ob,
                                           float& c, int tbase, size_t bbase,
                                           unsigned char* __restrict__ OUT8,
                                           int poff, int mode) {
#pragma unroll
  for (int i = 0; i < 8; ++i) {
    float z = 2.f / (1.f + __expf(-2.f * bf2f(zb[i]))) - 1.f;
    float f = 1.f / (1.f + __expf(-bf2f(fb[i])));
    float o = 1.f / (1.f + __expf(-bf2f(ob[i])));
    c = f * c + (1.f - f) * z;
    float h = o * c;
    int tt = tbase + i;
    size_t r = bbase + tt;
    unsigned char hb = f2e4m3(h);
    if (mode == 0) {
      OUT8[r * 1024 + 512 + poff] = hb;
      if (tt < TT - 1) OUT8[(r + 1) * 1024 + poff] = hb;
      if (tt == 0)     OUT8[r * 1024 + poff] = 0;
    } else {
      OUT8[r * 512 + poff] = hb;
    }
  }
}

__global__ __launch_bounds__(64) void scan_kernel(const ushort* __restrict__ PRE,
                                                  unsigned char* __restrict__ OUT8,
                                                  int mode) {
  int idx = blockIdx.x * 64 + threadIdx.x;    // 32*512
  int b = idx >> 9, d = idx & 511;
  const ushort* p = PRE + (size_t)b * TT * G3 + d;
  size_t bbase = (size_t)b * TT;
  int poff = physk(d);
  float c = 0.f;

  // named A/B prefetch buffers (rule #20: no runtime-indexed reg arrays)
  ushort zA[8], fA[8], oA[8], zB[8], fB[8], oB[8];
  scan_load(p, 0, zA, fA, oA);
#pragma unroll 1
  for (int t0 = 0; t0 < TT; t0 += 16) {
    scan_load(p, t0 + 8, zB, fB, oB);                      // prefetch next chunk
    scan_chunk(zA, fA, oA, c, t0, bbase, OUT8, poff, mode);
    if (t0 + 16 < TT) scan_load(p, t0 + 16, zA, fA, oA);   // prefetch next-next
    scan_chunk(zB, fB, oB, c, t0 + 8, bbase, OUT8, poff, mode);
  }
}

// ---------------- helpers ----------------
__global__ void zero_kernel(float* __restrict__ p, int n) {
  int i = blockIdx.x * 256 + threadIdx.x;
  if (i < n) p[i] = 0.f;
}

__global__ __launch_bounds__(256) void cost_kernel(const float* __restrict__ sumexp,
                                                   const float* __restrict__ tgl,
                                                   float* __restrict__ out) {
  int t = threadIdx.x;
  float s = 0.f;
  for (int r = t; r < R; r += 256) s += logf(sumexp[r]) - tgl[r];
#pragma unroll
  for (int m = 1; m < 64; m <<= 1) s += __shfl_xor(s, m, 64);
  __shared__ float red[4];
  int wave = t >> 6, lane = t & 63;
  if (lane == 0) red[wave] = s;
  __syncthreads();
  if (t == 0) out[0] = (red[0] + red[1] + red[2] + red[3]) / (float)R;
}

extern "C" void kernel_launch(void* const* d_in, const int* in_sizes, int n_in,
                              void* d_out, int out_size, void* d_ws, size_t ws_size,
                              hipStream_t stream) {
  const int*   tok = (const int*)d_in[0];
  const int*   tgt = (const int*)d_in[1];
  const float* emb = (const float*)d_in[2];
  const float* Wz0 = (const float*)d_in[3];  const float* bz0 = (const float*)d_in[4];
  const float* Wf0 = (const float*)d_in[5];  const float* bf0 = (const float*)d_in[6];
  const float* Wo0 = (const float*)d_in[7];  const float* bo0 = (const float*)d_in[8];
  const float* Wz1 = (const float*)d_in[9];  const float* bz1 = (const float*)d_in[10];
  const float* Wf1 = (const float*)d_in[11]; const float* bf1 = (const float*)d_in[12];
  const float* Wo1 = (const float*)d_in[13]; const float* bo1 = (const float*)d_in[14];
  const float* SW  = (const float*)d_in[15]; const float* SB  = (const float*)d_in[16];
  float* out = (float*)d_out;

  // workspace layout (bytes), total ~49.4 MB:
  char* base = (char*)d_ws;
  unsigned char* XA8 = (unsigned char*)(base);             //  8,388,608 [R][1024] fp8 phys-K
  unsigned char* YA8 = (unsigned char*)(base + 8388608);   //  8,388,608 [R][1024] fp8 phys-K
  ushort*        PRE = (ushort*)(base + 16777216);         // 25,165,824 [R][1536] bf16
  unsigned char* H8  = (unsigned char*)(base + 41943040);  //  4,194,304 [R][512]  fp8 phys-K
  unsigned char* WT80 = (unsigned char*)(base + 46137344); //  1,572,864 [1536][1024] fp8 phys-K
  unsigned char* WT81 = (unsigned char*)(base + 47710208); //  1,572,864
  float*         BC0 = (float*)(base + 49283072);          //  6,144
  float*         BC1 = (float*)(base + 49289216);          //  6,144
  float*         SUM = (float*)(base + 49295360);          //  32,768
  float*         TGL = (float*)(base + 49328128);          //  32,768
  unsigned char* SW8T = (unsigned char*)(base);            // 16,384,000 — aliases XA8+YA8 (dead by then)

  embed_kernel<<<R * 128 / 256, 256, 0, stream>>>(tok, (const float4*)emb, XA8);
  wconv<<<dim3(8, 8, 6), 256, 0, stream>>>(Wz0, Wf0, Wo0, WT80);
  wconv<<<dim3(8, 8, 6), 256, 0, stream>>>(Wz1, Wf1, Wo1, WT81);
  bcat_kernel<<<12, 256, 0, stream>>>(bz0, bf0, bo0, bz1, bf1, bo1, BC0, BC1);

  gemm_pre_fp8<<<dim3(64, 12), 256, 0, stream>>>(XA8, WT80, BC0, PRE);
  scan_kernel<<<256, 64, 0, stream>>>(PRE, YA8, 0);
  gemm_pre_fp8<<<dim3(64, 12), 256, 0, stream>>>(YA8, WT81, BC1, PRE);
  scan_kernel<<<256, 64, 0, stream>>>(PRE, H8, 1);

  // SW8T aliases XA8/YA8 — both dead after the second gemm_pre_fp8
  swconv<<<dim3(8, 500), 256, 0, stream>>>(SW, SW8T);
  zero_kernel<<<32, 256, 0, stream>>>(SUM, R);
  gemm_lse_fp8<<<dim3(64, 250), 256, 0, stream>>>(H8, SW8T, SB, tgt, SUM, TGL);
  cost_kernel<<<1, 256, 0, stream>>>(SUM, TGL, out);
}

// Round 13
// 395.258 us; speedup vs baseline: 2.0575x; 1.1894x over previous
//
#include <hip/hip_runtime.h>
#include <hip/hip_bf16.h>
#include <math.h>

// Problem constants (B=32, T=256, V=32000, D=512)
#define R   8192    // B*T rows
#define TT  256
#define D   512
#define V   32000
#define G3  1536    // 3*D (z|f|o)

typedef __attribute__((ext_vector_type(8))) short bf16x8;
typedef __attribute__((ext_vector_type(4))) float f32x4;
typedef __attribute__((ext_vector_type(4))) int   i32x4;
typedef __attribute__((ext_vector_type(8))) int   i32x8;

__device__ __forceinline__ float bf2f(ushort u) {
  union { unsigned int i; float f; } x; x.i = ((unsigned int)u) << 16; return x.f;
}
__device__ __forceinline__ ushort f2bf(float f) {   // RNE
  union { float f; unsigned int i; } x; x.f = f;
  unsigned int r = x.i + 0x7fffu + ((x.i >> 16) & 1u);
  return (ushort)(r >> 16);
}

// f32 -> OCP e4m3fn, round-nearest-even, clamp to 448. Exact integer-grid method.
__device__ __forceinline__ unsigned char f2e4m3(float f) {
  unsigned char s = (__float_as_uint(f) >> 31) ? 0x80 : 0x00;
  float a = fabsf(f);
  if (!(a < 448.f)) return s | 0x7e;       // clamp (no NaN/overflow in our data)
  if (a == 0.f) return s;
  int ef; frexpf(a, &ef);                  // a = m*2^ef, m in [0.5,1)
  int E = ef - 1;                          // a = (2m)*2^E
  if (E < -6) E = -6;                      // denormal grid
  float ulp = ldexpf(1.f, E - 3);
  int qi = (int)rintf(a / ulp);            // exact scale (pow2), RNE, qi in [0,16]
  if (qi >= 16) { E += 1; qi = 8; }
  unsigned char bits = (qi < 8) ? (unsigned char)qi
                                : (unsigned char)(((E + 7) << 3) | (qi - 8));
  return s | bits;
}

// OCP e4m3fn -> f32 (exact decode; 0x7f NaN never produced by f2e4m3)
__device__ __forceinline__ float e4m3f(unsigned char b) {
  int e = (b >> 3) & 15, m = b & 7;
  float v;
  if (e == 0) v = (float)m * 0.001953125f;            // m * 2^-9
  else { union { unsigned u; float f; } x;
         x.u = ((unsigned)(e + 120) << 23) | ((unsigned)m << 20); v = x.f; }
  return (b & 0x80) ? -v : v;
}

// phys-K transpose within each 128-elem block: element k stored at
// poff(k) = (k&~127) | h*32 | ks*8 | j  where k = (k&~127)+ks*32+h*8+j.
__device__ __forceinline__ int physk(int d) {
  return (d & ~127) | (((d >> 3) & 3) << 5) | (((d >> 5) & 3) << 3) | (d & 7);
}

__device__ __forceinline__ void gload16(const void* g, void* l) {
  __builtin_amdgcn_global_load_lds((const __attribute__((address_space(1))) void*)g,
                                   (__attribute__((address_space(3))) void*)l, 16, 0, 0);
}

// ---------------- embedding gather -> XA8 fp8 phys-K [R][1024] = [x_prev | x] ----------------
__global__ __launch_bounds__(256) void embed_kernel(const int* __restrict__ tok,
                                                    const float4* __restrict__ emb,
                                                    unsigned char* __restrict__ XA8) {
  int idx = blockIdx.x * 256 + threadIdx.x;   // over R*128 float4s
  int r = idx >> 7, d4 = idx & 127;
  float4 v = emb[(size_t)tok[r] * 128 + d4];
  uchar4 h8;
  h8.x = f2e4m3(v.x); h8.y = f2e4m3(v.y); h8.z = f2e4m3(v.z); h8.w = f2e4m3(v.w);
  int pp = physk(d4 * 4);                     // aligned-4 contiguous run
  *(uchar4*)(XA8 + (size_t)r * 1024 + 512 + pp) = h8;          // x part
  int t = r & (TT - 1);
  if (t < TT - 1) *(uchar4*)(XA8 + (size_t)(r + 1) * 1024 + pp) = h8;  // next row x_prev
  if (t == 0) { uchar4 z = {0, 0, 0, 0}; *(uchar4*)(XA8 + (size_t)r * 1024 + pp) = z; }
}

// ---------------- coalesced fp8 phys-K transpose-convert helper ----------------
__device__ __forceinline__ void tconv_write(const float (*tile)[65],
                                            unsigned char* __restrict__ dstrow0,
                                            size_t ldb, int k0, int t) {
  int nn = t & 63, h = t >> 6;
  union { unsigned char c[16]; uint4 q; } u;
#pragma unroll
  for (int ksl = 0; ksl < 2; ++ksl)
#pragma unroll
    for (int j = 0; j < 8; ++j)
      u.c[ksl * 8 + j] = f2e4m3(tile[ksl * 32 + h * 8 + j][nn]);
  unsigned char* dst = dstrow0 + (size_t)nn * ldb + (k0 & ~127) + h * 32 + ((k0 & 64) ? 16 : 0);
  *(uint4*)dst = u.q;
}

// ---------------- weight transpose+convert: WT8[1536][1024] fp8 phys-K ----------------
__global__ __launch_bounds__(256) void wconv(const float* __restrict__ Wz,
                                             const float* __restrict__ Wf,
                                             const float* __restrict__ Wo,
                                             unsigned char* __restrict__ WT8) {
  __shared__ float tile[64][65];
  int z = blockIdx.z, g = z >> 1, i = z & 1;
  const float* src = (g == 0) ? Wz : (g == 1 ? Wf : Wo);
  src += (size_t)i * D * D;
  int d0 = blockIdx.x * 64, e0 = blockIdx.y * 64;
  int t = threadIdx.x, c = t & 63, rq = t >> 6;
#pragma unroll
  for (int p = 0; p < 16; ++p) {
    int dd = p * 4 + rq;
    tile[dd][c] = src[(size_t)(d0 + dd) * D + e0 + c];   // [k=d][n=e]
  }
  __syncthreads();
  tconv_write(tile, WT8 + (size_t)(g * D + e0) * 1024, 1024, i * 512 + d0, t);
}

// ---------------- softmax weight transpose+convert: SW8T[32000][512] fp8 phys-K ----------------
__global__ __launch_bounds__(256) void swconv(const float* __restrict__ SW,
                                              unsigned char* __restrict__ SWT) {
  __shared__ float tile[64][65];
  int k0 = blockIdx.x * 64, n0 = blockIdx.y * 64;
  int t = threadIdx.x, c = t & 63, rq = t >> 6;
#pragma unroll
  for (int p = 0; p < 16; ++p) {
    int kk = p * 4 + rq;
    tile[kk][c] = SW[(size_t)(k0 + kk) * V + n0 + c];
  }
  __syncthreads();
  tconv_write(tile, SWT + (size_t)n0 * 512, 512, k0, t);
}

// ---------------- bias concat ----------------
__global__ void bcat_kernel(const float* bz0, const float* bf0, const float* bo0,
                            const float* bz1, const float* bf1, const float* bo1,
                            float* BC0, float* BC1) {
  int idx = blockIdx.x * 256 + threadIdx.x;
  if (idx >= 2 * G3) return;
  int layer = idx / G3, rem = idx % G3, g = rem >> 9, e = rem & 511;
  const float* s = (layer == 0) ? (g == 0 ? bz0 : (g == 1 ? bf0 : bo0))
                                : (g == 0 ? bz1 : (g == 1 ? bf1 : bo1));
  (layer == 0 ? BC0 : BC1)[rem] = s[e];
}

// ---------------- shared MX-fp8 128x128 GEMM core (VERIFIED r9/r10) ----------------
// 256 thr / 4 waves (2x2 of 64x64), BK=128, 32KB LDS single-buffered.
// Swapped MFMA (mfma(b8,a8)): C row = lane&15 (lane-local), C col = (lane>>4)*4+j.
template<int LD, int NKT>
__device__ __forceinline__ void mx_core(const unsigned char* __restrict__ A,
                                        const unsigned char* __restrict__ B,
                                        int row0, int col0, char* lds,
                                        f32x4 acc[4][4]) {
  char* As = lds;
  char* Bs = lds + 16384;
  const int t = threadIdx.x, lane = t & 63, w = t >> 6;
  const int wm = w >> 1, wn = w & 1;
  const int lo = lane & 15, hi = lane >> 4;
  const int gr = t >> 3;             // row within 32-row issue
  const int ss = (t & 7) ^ (gr & 7); // inverse-swizzled source slot
  const int x  = lo & 7;             // frag-read row swizzle

#pragma unroll 1
  for (int kt = 0; kt < NKT; ++kt) {
    const int k0 = kt * 128;
#pragma unroll
    for (int i = 0; i < 4; ++i) {
      gload16(A + (size_t)(row0 + i * 32 + gr) * LD + k0 + ss * 16,
              As + i * 4096 + t * 16);
      gload16(B + (size_t)(col0 + i * 32 + gr) * LD + k0 + ss * 16,
              Bs + i * 4096 + t * 16);
    }
    __syncthreads();
    i32x8 b8[4];
#pragma unroll
    for (int ni = 0; ni < 4; ++ni) {
      const char* rb = Bs + (wn * 64 + ni * 16 + lo) * 128;
      union { i32x8 v8; i32x4 v4[2]; } u;
      u.v4[0] = *(const i32x4*)(rb + ((hi * 2 + 0) ^ x) * 16);
      u.v4[1] = *(const i32x4*)(rb + ((hi * 2 + 1) ^ x) * 16);
      b8[ni] = u.v8;
    }
#pragma unroll
    for (int mi = 0; mi < 4; ++mi) {
      const char* rb = As + (wm * 64 + mi * 16 + lo) * 128;
      union { i32x8 v8; i32x4 v4[2]; } u;
      u.v4[0] = *(const i32x4*)(rb + ((hi * 2 + 0) ^ x) * 16);
      u.v4[1] = *(const i32x4*)(rb + ((hi * 2 + 1) ^ x) * 16);
      i32x8 a8 = u.v8;
#pragma unroll
      for (int ni = 0; ni < 4; ++ni)
        acc[mi][ni] = __builtin_amdgcn_mfma_scale_f32_16x16x128_f8f6f4(
            b8[ni], a8, acc[mi][ni], 0, 0, 0, 0x7F, 0, 0x7F);
    }
    __syncthreads();
  }
}

// ---------------- QRNN pre-activation GEMM (8192x1536x1024, MX-fp8) — r10 exact ----------------
__global__ __launch_bounds__(256, 2) void gemm_pre_fp8(const unsigned char* __restrict__ A,
                                                       const unsigned char* __restrict__ B,
                                                       const float* __restrict__ bcat,
                                                       ushort* __restrict__ PRE) {
  __shared__ char lds[32768];
  const int t = threadIdx.x, lane = t & 63, w = t >> 6;
  const int wm = w >> 1, wn = w & 1;
  const int lo = lane & 15, hi = lane >> 4;
  const int row0 = blockIdx.x * 128, col0 = blockIdx.y * 128;

  f32x4 acc[4][4];
#pragma unroll
  for (int i = 0; i < 4; ++i)
#pragma unroll
    for (int j = 0; j < 4; ++j) { f32x4 z = {0.f,0.f,0.f,0.f}; acc[i][j] = z; }

  mx_core<1024, 8>(A, B, row0, col0, lds, acc);

  // swapped layout: row = +lo (lane-local), col = colb + j -> ushort4 stores
#pragma unroll
  for (int mi = 0; mi < 4; ++mi) {
    const int row = row0 + wm * 64 + mi * 16 + lo;
#pragma unroll
    for (int ni = 0; ni < 4; ++ni) {
      const int colb = col0 + wn * 64 + ni * 16 + hi * 4;
      ushort4 v;
      v.x = f2bf(acc[mi][ni][0] + bcat[colb + 0]);
      v.y = f2bf(acc[mi][ni][1] + bcat[colb + 1]);
      v.z = f2bf(acc[mi][ni][2] + bcat[colb + 2]);
      v.w = f2bf(acc[mi][ni][3] + bcat[colb + 3]);
      *(ushort4*)(PRE + (size_t)row * G3 + colb) = v;
    }
  }
}

// ---------------- target-logit kernel: TGL[row] = dot(H8[row], SW8T[tgt[row]]) + SB[tgt] ----------------
// Both operands share the phys-K permutation -> elementwise product sums correctly.
// Matches the MFMA logit up to f32 accumulation order (<<1e-3, threshold 0.2).
__global__ __launch_bounds__(256) void tgl_kernel(const unsigned char* __restrict__ H8,
                                                  const unsigned char* __restrict__ SWT,
                                                  const float* __restrict__ SB,
                                                  const int* __restrict__ tgt,
                                                  float* __restrict__ TGL) {
  int wid  = (blockIdx.x * 256 + threadIdx.x) >> 6;   // one wave per row
  int lane = threadIdx.x & 63;
  int tg = tgt[wid];
  uint2 hv = *(const uint2*)(H8  + (size_t)wid * 512 + lane * 8);
  uint2 wv = *(const uint2*)(SWT + (size_t)tg  * 512 + lane * 8);
  float s = 0.f;
#pragma unroll
  for (int k = 0; k < 4; ++k)
    s += e4m3f((hv.x >> (8 * k)) & 255) * e4m3f((wv.x >> (8 * k)) & 255);
#pragma unroll
  for (int k = 0; k < 4; ++k)
    s += e4m3f((hv.y >> (8 * k)) & 255) * e4m3f((wv.y >> (8 * k)) & 255);
#pragma unroll
  for (int m = 1; m < 64; m <<= 1) s += __shfl_xor(s, m, 64);
  if (lane == 0) TGL[wid] = s + SB[tg];
}

// ---------------- MX-fp8 logits GEMM + fused exp-sum (slim epilogue, no target capture) ----------------
__global__ __launch_bounds__(256, 2) void gemm_lse_fp8(const unsigned char* __restrict__ A,
                                                       const unsigned char* __restrict__ B,
                                                       const float* __restrict__ SB,
                                                       float* __restrict__ SUM) {
  __shared__ char lds[32768];
  const int t = threadIdx.x, lane = t & 63, w = t >> 6;
  const int wm = w >> 1, wn = w & 1;
  const int lo = lane & 15, hi = lane >> 4;
  const int row0 = blockIdx.x * 128, col0 = blockIdx.y * 128;

  // preload bias (uniform per thread) before the K-loop: hides latency
  float sb[16];
#pragma unroll
  for (int ni = 0; ni < 4; ++ni)
#pragma unroll
    for (int j = 0; j < 4; ++j)
      sb[ni * 4 + j] = SB[col0 + wn * 64 + ni * 16 + hi * 4 + j];

  f32x4 acc[4][4];
#pragma unroll
  for (int i = 0; i < 4; ++i)
#pragma unroll
    for (int j = 0; j < 4; ++j) { f32x4 z = {0.f,0.f,0.f,0.f}; acc[i][j] = z; }

  mx_core<512, 4>(A, B, row0, col0, lds, acc);

  // epilogue (swapped layout): out_row = row0+wm*64+mi*16+lo (lane-local).
  // 4 independent partial sums break the 64-deep dependent add chain.
#pragma unroll
  for (int mi = 0; mi < 4; ++mi) {
    const int row = row0 + wm * 64 + mi * 16 + lo;
    float s0 = 0.f, s1 = 0.f, s2 = 0.f, s3 = 0.f;
#pragma unroll
    for (int ni = 0; ni < 4; ++ni) {
      s0 += __expf(acc[mi][ni][0] + sb[ni * 4 + 0]);
      s1 += __expf(acc[mi][ni][1] + sb[ni * 4 + 1]);
      s2 += __expf(acc[mi][ni][2] + sb[ni * 4 + 2]);
      s3 += __expf(acc[mi][ni][3] + sb[ni * 4 + 3]);
    }
    float s = (s0 + s1) + (s2 + s3);
    s += __shfl_xor(s, 16, 64);
    s += __shfl_xor(s, 32, 64);
    if (hi == 0) atomicAdd(&SUM[row], s);
  }
}

// ---------------- fo-pool scan (r10 exact; bf16 in, fp8 phys-K out) ----------------
__global__ __launch_bounds__(64) void scan_kernel(const ushort* __restrict__ PRE,
                                                  unsigned char* __restrict__ OUT8,
                                                  int mode) {
  int idx = blockIdx.x * 64 + threadIdx.x;    // 32*512
  int b = idx >> 9, d = idx & 511;
  const ushort* p = PRE + (size_t)b * TT * G3 + d;
  int poff = physk(d);
  float c = 0.f;
  for (int t0 = 0; t0 < TT; t0 += 8) {
    float pz[8], pf[8], po[8];
#pragma unroll
    for (int i = 0; i < 8; ++i) {
      const ushort* q = p + (size_t)(t0 + i) * G3;
      pz[i] = bf2f(q[0]); pf[i] = bf2f(q[512]); po[i] = bf2f(q[1024]);
    }
#pragma unroll
    for (int i = 0; i < 8; ++i) {
      float z = 2.f / (1.f + __expf(-2.f * pz[i])) - 1.f;
      float f = 1.f / (1.f + __expf(-pf[i]));
      float o = 1.f / (1.f + __expf(-po[i]));
      c = f * c + (1.f - f) * z;
      float h = o * c;
      int tt = t0 + i;
      size_t r = (size_t)b * TT + tt;
      unsigned char hb = f2e4m3(h);
      if (mode == 0) {
        OUT8[r * 1024 + 512 + poff] = hb;
        if (tt < TT - 1) OUT8[(r + 1) * 1024 + poff] = hb;
        if (tt == 0)     OUT8[r * 1024 + poff] = 0;
      } else {
        OUT8[r * 512 + poff] = hb;
      }
    }
  }
}

// ---------------- helpers ----------------
__global__ void zero_kernel(float* __restrict__ p, int n) {
  int i = blockIdx.x * 256 + threadIdx.x;
  if (i < n) p[i] = 0.f;
}

__global__ __launch_bounds__(256) void cost_kernel(const float* __restrict__ sumexp,
                                                   const float* __restrict__ tgl,
                                                   float* __restrict__ out) {
  int t = threadIdx.x;
  float s = 0.f;
  for (int r = t; r < R; r += 256) s += logf(sumexp[r]) - tgl[r];
#pragma unroll
  for (int m = 1; m < 64; m <<= 1) s += __shfl_xor(s, m, 64);
  __shared__ float red[4];
  int wave = t >> 6, lane = t & 63;
  if (lane == 0) red[wave] = s;
  __syncthreads();
  if (t == 0) out[0] = (red[0] + red[1] + red[2] + red[3]) / (float)R;
}

extern "C" void kernel_launch(void* const* d_in, const int* in_sizes, int n_in,
                              void* d_out, int out_size, void* d_ws, size_t ws_size,
                              hipStream_t stream) {
  const int*   tok = (const int*)d_in[0];
  const int*   tgt = (const int*)d_in[1];
  const float* emb = (const float*)d_in[2];
  const float* Wz0 = (const float*)d_in[3];  const float* bz0 = (const float*)d_in[4];
  const float* Wf0 = (const float*)d_in[5];  const float* bf0 = (const float*)d_in[6];
  const float* Wo0 = (const float*)d_in[7];  const float* bo0 = (const float*)d_in[8];
  const float* Wz1 = (const float*)d_in[9];  const float* bz1 = (const float*)d_in[10];
  const float* Wf1 = (const float*)d_in[11]; const float* bf1 = (const float*)d_in[12];
  const float* Wo1 = (const float*)d_in[13]; const float* bo1 = (const float*)d_in[14];
  const float* SW  = (const float*)d_in[15]; const float* SB  = (const float*)d_in[16];
  float* out = (float*)d_out;

  // workspace layout (bytes), total ~49.4 MB:
  char* base = (char*)d_ws;
  unsigned char* XA8 = (unsigned char*)(base);             //  8,388,608 [R][1024] fp8 phys-K
  unsigned char* YA8 = (unsigned char*)(base + 8388608);   //  8,388,608 [R][1024] fp8 phys-K
  ushort*        PRE = (ushort*)(base + 16777216);         // 25,165,824 [R][1536] bf16
  unsigned char* H8  = (unsigned char*)(base + 41943040);  //  4,194,304 [R][512]  fp8 phys-K
  unsigned char* WT80 = (unsigned char*)(base + 46137344); //  1,572,864 [1536][1024] fp8 phys-K
  unsigned char* WT81 = (unsigned char*)(base + 47710208); //  1,572,864
  float*         BC0 = (float*)(base + 49283072);          //  6,144
  float*         BC1 = (float*)(base + 49289216);          //  6,144
  float*         SUM = (float*)(base + 49295360);          //  32,768
  float*         TGL = (float*)(base + 49328128);          //  32,768
  unsigned char* SW8T = (unsigned char*)(base);            // 16,384,000 — aliases XA8+YA8 (dead by then)

  embed_kernel<<<R * 128 / 256, 256, 0, stream>>>(tok, (const float4*)emb, XA8);
  wconv<<<dim3(8, 8, 6), 256, 0, stream>>>(Wz0, Wf0, Wo0, WT80);
  wconv<<<dim3(8, 8, 6), 256, 0, stream>>>(Wz1, Wf1, Wo1, WT81);
  bcat_kernel<<<12, 256, 0, stream>>>(bz0, bf0, bo0, bz1, bf1, bo1, BC0, BC1);

  gemm_pre_fp8<<<dim3(64, 12), 256, 0, stream>>>(XA8, WT80, BC0, PRE);
  scan_kernel<<<256, 64, 0, stream>>>(PRE, YA8, 0);
  gemm_pre_fp8<<<dim3(64, 12), 256, 0, stream>>>(YA8, WT81, BC1, PRE);
  scan_kernel<<<256, 64, 0, stream>>>(PRE, H8, 1);

  // SW8T aliases XA8/YA8 — both dead after the second gemm_pre_fp8
  swconv<<<dim3(8, 500), 256, 0, stream>>>(SW, SW8T);
  zero_kernel<<<32, 256, 0, stream>>>(SUM, R);
  tgl_kernel<<<R / 4, 256, 0, stream>>>(H8, SW8T, SB, tgt, TGL);
  gemm_lse_fp8<<<dim3(64, 250), 256, 0, stream>>>(H8, SW8T, SB, SUM);
  cost_kernel<<<1, 256, 0, stream>>>(SUM, TGL, out);
}

// Round 14
// 323.200 us; speedup vs baseline: 2.5162x; 1.2230x over previous
//
#include <hip/hip_runtime.h>
#include <hip/hip_bf16.h>
#include <math.h>

// Problem constants (B=32, T=256, V=32000, D=512)
#define R   8192    // B*T rows
#define TT  256
#define D   512
#define V   32000
#define G3  1536    // 3*D (z|f|o)

typedef __attribute__((ext_vector_type(8))) short bf16x8;
typedef __attribute__((ext_vector_type(4))) float f32x4;
typedef __attribute__((ext_vector_type(4))) int   i32x4;
typedef __attribute__((ext_vector_type(8))) int   i32x8;

__device__ __forceinline__ float bf2f(ushort u) {
  union { unsigned int i; float f; } x; x.i = ((unsigned int)u) << 16; return x.f;
}
__device__ __forceinline__ ushort f2bf(float f) {   // RNE
  union { float f; unsigned int i; } x; x.f = f;
  unsigned int r = x.i + 0x7fffu + ((x.i >> 16) & 1u);
  return (ushort)(r >> 16);
}

// f32 -> OCP e4m3fn, round-nearest-even, clamp to 448. Exact integer-grid method.
__device__ __forceinline__ unsigned char f2e4m3(float f) {
  unsigned char s = (__float_as_uint(f) >> 31) ? 0x80 : 0x00;
  float a = fabsf(f);
  if (!(a < 448.f)) return s | 0x7e;       // clamp (no NaN/overflow in our data)
  if (a == 0.f) return s;
  int ef; frexpf(a, &ef);                  // a = m*2^ef, m in [0.5,1)
  int E = ef - 1;                          // a = (2m)*2^E
  if (E < -6) E = -6;                      // denormal grid
  float ulp = ldexpf(1.f, E - 3);
  int qi = (int)rintf(a / ulp);            // exact scale (pow2), RNE, qi in [0,16]
  if (qi >= 16) { E += 1; qi = 8; }
  unsigned char bits = (qi < 8) ? (unsigned char)qi
                                : (unsigned char)(((E + 7) << 3) | (qi - 8));
  return s | bits;
}

// OCP e4m3fn -> f32 (exact decode; 0x7f NaN never produced by f2e4m3)
__device__ __forceinline__ float e4m3f(unsigned char b) {
  int e = (b >> 3) & 15, m = b & 7;
  float v;
  if (e == 0) v = (float)m * 0.001953125f;            // m * 2^-9
  else { union { unsigned u; float f; } x;
         x.u = ((unsigned)(e + 120) << 23) | ((unsigned)m << 20); v = x.f; }
  return (b & 0x80) ? -v : v;
}

// phys-K transpose within each 128-elem block: element k stored at
// poff(k) = (k&~127) | h*32 | ks*8 | j  where k = (k&~127)+ks*32+h*8+j.
__device__ __forceinline__ int physk(int d) {
  return (d & ~127) | (((d >> 3) & 3) << 5) | (((d >> 5) & 3) << 3) | (d & 7);
}

__device__ __forceinline__ void gload16(const void* g, void* l) {
  __builtin_amdgcn_global_load_lds((const __attribute__((address_space(1))) void*)g,
                                   (__attribute__((address_space(3))) void*)l, 16, 0, 0);
}

// ---------------- embedding gather -> XA8 fp8 phys-K [R][1024] = [x_prev | x] ----------------
__global__ __launch_bounds__(256) void embed_kernel(const int* __restrict__ tok,
                                                    const float4* __restrict__ emb,
                                                    unsigned char* __restrict__ XA8) {
  int idx = blockIdx.x * 256 + threadIdx.x;   // over R*128 float4s
  int r = idx >> 7, d4 = idx & 127;
  float4 v = emb[(size_t)tok[r] * 128 + d4];
  uchar4 h8;
  h8.x = f2e4m3(v.x); h8.y = f2e4m3(v.y); h8.z = f2e4m3(v.z); h8.w = f2e4m3(v.w);
  int pp = physk(d4 * 4);                     // aligned-4 contiguous run
  *(uchar4*)(XA8 + (size_t)r * 1024 + 512 + pp) = h8;          // x part
  int t = r & (TT - 1);
  if (t < TT - 1) *(uchar4*)(XA8 + (size_t)(r + 1) * 1024 + pp) = h8;  // next row x_prev
  if (t == 0) { uchar4 z = {0, 0, 0, 0}; *(uchar4*)(XA8 + (size_t)r * 1024 + pp) = z; }
}

// ---------------- coalesced fp8 phys-K transpose-convert helper ----------------
__device__ __forceinline__ void tconv_write(const float (*tile)[65],
                                            unsigned char* __restrict__ dstrow0,
                                            size_t ldb, int k0, int t) {
  int nn = t & 63, h = t >> 6;
  union { unsigned char c[16]; uint4 q; } u;
#pragma unroll
  for (int ksl = 0; ksl < 2; ++ksl)
#pragma unroll
    for (int j = 0; j < 8; ++j)
      u.c[ksl * 8 + j] = f2e4m3(tile[ksl * 32 + h * 8 + j][nn]);
  unsigned char* dst = dstrow0 + (size_t)nn * ldb + (k0 & ~127) + h * 32 + ((k0 & 64) ? 16 : 0);
  *(uint4*)dst = u.q;
}

// ---------------- weight transpose+convert: WT8[1536][1024] fp8 phys-K ----------------
__global__ __launch_bounds__(256) void wconv(const float* __restrict__ Wz,
                                             const float* __restrict__ Wf,
                                             const float* __restrict__ Wo,
                                             unsigned char* __restrict__ WT8) {
  __shared__ float tile[64][65];
  int z = blockIdx.z, g = z >> 1, i = z & 1;
  const float* src = (g == 0) ? Wz : (g == 1 ? Wf : Wo);
  src += (size_t)i * D * D;
  int d0 = blockIdx.x * 64, e0 = blockIdx.y * 64;
  int t = threadIdx.x, c = t & 63, rq = t >> 6;
#pragma unroll
  for (int p = 0; p < 16; ++p) {
    int dd = p * 4 + rq;
    tile[dd][c] = src[(size_t)(d0 + dd) * D + e0 + c];   // [k=d][n=e]
  }
  __syncthreads();
  tconv_write(tile, WT8 + (size_t)(g * D + e0) * 1024, 1024, i * 512 + d0, t);
}

// ---------------- softmax weight transpose+convert: SW8T[32000][512] fp8 phys-K ----------------
__global__ __launch_bounds__(256) void swconv(const float* __restrict__ SW,
                                              unsigned char* __restrict__ SWT) {
  __shared__ float tile[64][65];
  int k0 = blockIdx.x * 64, n0 = blockIdx.y * 64;
  int t = threadIdx.x, c = t & 63, rq = t >> 6;
#pragma unroll
  for (int p = 0; p < 16; ++p) {
    int kk = p * 4 + rq;
    tile[kk][c] = SW[(size_t)(k0 + kk) * V + n0 + c];
  }
  __syncthreads();
  tconv_write(tile, SWT + (size_t)n0 * 512, 512, k0, t);
}

// ---------------- bias concat ----------------
__global__ void bcat_kernel(const float* bz0, const float* bf0, const float* bo0,
                            const float* bz1, const float* bf1, const float* bo1,
                            float* BC0, float* BC1) {
  int idx = blockIdx.x * 256 + threadIdx.x;
  if (idx >= 2 * G3) return;
  int layer = idx / G3, rem = idx % G3, g = rem >> 9, e = rem & 511;
  const float* s = (layer == 0) ? (g == 0 ? bz0 : (g == 1 ? bf0 : bo0))
                                : (g == 0 ? bz1 : (g == 1 ? bf1 : bo1));
  (layer == 0 ? BC0 : BC1)[rem] = s[e];
}

// ---------------- MX-fp8 256x128 GEMM core (scaled-up r9/r10 core) ----------------
// 256 thr / 4 waves; wave tile 128x64 (wm 0..1 over 128 M-rows, wn 0..1 over 64 N).
// BK=128, LDS = A 32KB + B 16KB = 48KB single-buffered -> 2 blocks/CU.
// Swapped MFMA (mfma(b8,a8)): C row = lane&15 (lane-local), C col = (lane>>4)*4+j.
// vs 128x128: LDS bytes+conflicts per output x0.75, barrier drains per MFMA x0.5.
template<int LD, int NKT>
__device__ __forceinline__ void mx_core256(const unsigned char* __restrict__ A,
                                           const unsigned char* __restrict__ B,
                                           int row0, int col0, char* lds,
                                           f32x4 acc[8][4]) {
  char* As = lds;            // 256 rows x 128B
  char* Bs = lds + 32768;    // 128 rows x 128B
  const int t = threadIdx.x, lane = t & 63, w = t >> 6;
  const int wm = w >> 1, wn = w & 1;
  const int lo = lane & 15, hi = lane >> 4;
  const int gr = t >> 3;             // row within 32-row issue
  const int ss = (t & 7) ^ (gr & 7); // inverse-swizzled source slot
  const int x  = lo & 7;             // frag-read row swizzle

#pragma unroll 1
  for (int kt = 0; kt < NKT; ++kt) {
    const int k0 = kt * 128;
#pragma unroll
    for (int i = 0; i < 8; ++i)
      gload16(A + (size_t)(row0 + i * 32 + gr) * LD + k0 + ss * 16,
              As + i * 4096 + t * 16);
#pragma unroll
    for (int i = 0; i < 4; ++i)
      gload16(B + (size_t)(col0 + i * 32 + gr) * LD + k0 + ss * 16,
              Bs + i * 4096 + t * 16);
    __syncthreads();
    i32x8 b8[4];
#pragma unroll
    for (int ni = 0; ni < 4; ++ni) {
      const char* rb = Bs + (wn * 64 + ni * 16 + lo) * 128;
      union { i32x8 v8; i32x4 v4[2]; } u;
      u.v4[0] = *(const i32x4*)(rb + ((hi * 2 + 0) ^ x) * 16);
      u.v4[1] = *(const i32x4*)(rb + ((hi * 2 + 1) ^ x) * 16);
      b8[ni] = u.v8;
    }
#pragma unroll
    for (int mi = 0; mi < 8; ++mi) {
      const char* rb = As + (wm * 128 + mi * 16 + lo) * 128;
      union { i32x8 v8; i32x4 v4[2]; } u;
      u.v4[0] = *(const i32x4*)(rb + ((hi * 2 + 0) ^ x) * 16);
      u.v4[1] = *(const i32x4*)(rb + ((hi * 2 + 1) ^ x) * 16);
      i32x8 a8 = u.v8;
#pragma unroll
      for (int ni = 0; ni < 4; ++ni)
        acc[mi][ni] = __builtin_amdgcn_mfma_scale_f32_16x16x128_f8f6f4(
            b8[ni], a8, acc[mi][ni], 0, 0, 0, 0x7F, 0, 0x7F);
    }
    __syncthreads();
  }
}

// ---------------- QRNN pre-activation GEMM (8192x1536x1024, MX-fp8, 256x128) ----------------
__global__ __launch_bounds__(256, 2) void gemm_pre_fp8(const unsigned char* __restrict__ A,
                                                       const unsigned char* __restrict__ B,
                                                       const float* __restrict__ bcat,
                                                       ushort* __restrict__ PRE) {
  __shared__ char lds[49152];
  const int t = threadIdx.x, lane = t & 63, w = t >> 6;
  const int wm = w >> 1, wn = w & 1;
  const int lo = lane & 15, hi = lane >> 4;
  const int row0 = blockIdx.x * 256, col0 = blockIdx.y * 128;

  f32x4 acc[8][4];
#pragma unroll
  for (int i = 0; i < 8; ++i)
#pragma unroll
    for (int j = 0; j < 4; ++j) { f32x4 z = {0.f,0.f,0.f,0.f}; acc[i][j] = z; }

  mx_core256<1024, 8>(A, B, row0, col0, lds, acc);

  // swapped layout: row = +lo (lane-local), col = colb + j -> ushort4 stores
#pragma unroll
  for (int mi = 0; mi < 8; ++mi) {
    const int row = row0 + wm * 128 + mi * 16 + lo;
#pragma unroll
    for (int ni = 0; ni < 4; ++ni) {
      const int colb = col0 + wn * 64 + ni * 16 + hi * 4;
      ushort4 v;
      v.x = f2bf(acc[mi][ni][0] + bcat[colb + 0]);
      v.y = f2bf(acc[mi][ni][1] + bcat[colb + 1]);
      v.z = f2bf(acc[mi][ni][2] + bcat[colb + 2]);
      v.w = f2bf(acc[mi][ni][3] + bcat[colb + 3]);
      *(ushort4*)(PRE + (size_t)row * G3 + colb) = v;
    }
  }
}

// ---------------- target-logit kernel: TGL[row] = dot(H8[row], SW8T[tgt[row]]) + SB[tgt] ----------------
__global__ __launch_bounds__(256) void tgl_kernel(const unsigned char* __restrict__ H8,
                                                  const unsigned char* __restrict__ SWT,
                                                  const float* __restrict__ SB,
                                                  const int* __restrict__ tgt,
                                                  float* __restrict__ TGL) {
  int wid  = (blockIdx.x * 256 + threadIdx.x) >> 6;   // one wave per row
  int lane = threadIdx.x & 63;
  int tg = tgt[wid];
  uint2 hv = *(const uint2*)(H8  + (size_t)wid * 512 + lane * 8);
  uint2 wv = *(const uint2*)(SWT + (size_t)tg  * 512 + lane * 8);
  float s = 0.f;
#pragma unroll
  for (int k = 0; k < 4; ++k)
    s += e4m3f((hv.x >> (8 * k)) & 255) * e4m3f((wv.x >> (8 * k)) & 255);
#pragma unroll
  for (int k = 0; k < 4; ++k)
    s += e4m3f((hv.y >> (8 * k)) & 255) * e4m3f((wv.y >> (8 * k)) & 255);
#pragma unroll
  for (int m = 1; m < 64; m <<= 1) s += __shfl_xor(s, m, 64);
  if (lane == 0) TGL[wid] = s + SB[tg];
}

// ---------------- MX-fp8 logits GEMM + fused exp-sum (256x128, slim epilogue) ----------------
__global__ __launch_bounds__(256, 2) void gemm_lse_fp8(const unsigned char* __restrict__ A,
                                                       const unsigned char* __restrict__ B,
                                                       const float* __restrict__ SB,
                                                       float* __restrict__ SUM) {
  __shared__ char lds[49152];
  const int t = threadIdx.x, lane = t & 63, w = t >> 6;
  const int wm = w >> 1, wn = w & 1;
  const int lo = lane & 15, hi = lane >> 4;
  const int row0 = blockIdx.x * 256, col0 = blockIdx.y * 128;

  // preload bias (uniform per thread) before the K-loop: hides latency
  float sb[16];
#pragma unroll
  for (int ni = 0; ni < 4; ++ni)
#pragma unroll
    for (int j = 0; j < 4; ++j)
      sb[ni * 4 + j] = SB[col0 + wn * 64 + ni * 16 + hi * 4 + j];

  f32x4 acc[8][4];
#pragma unroll
  for (int i = 0; i < 8; ++i)
#pragma unroll
    for (int j = 0; j < 4; ++j) { f32x4 z = {0.f,0.f,0.f,0.f}; acc[i][j] = z; }

  mx_core256<512, 4>(A, B, row0, col0, lds, acc);

  // epilogue (swapped layout): out_row = row0+wm*128+mi*16+lo (lane-local).
  // 4 independent partial sums break the dependent add chain.
#pragma unroll
  for (int mi = 0; mi < 8; ++mi) {
    const int row = row0 + wm * 128 + mi * 16 + lo;
    float s0 = 0.f, s1 = 0.f, s2 = 0.f, s3 = 0.f;
#pragma unroll
    for (int ni = 0; ni < 4; ++ni) {
      s0 += __expf(acc[mi][ni][0] + sb[ni * 4 + 0]);
      s1 += __expf(acc[mi][ni][1] + sb[ni * 4 + 1]);
      s2 += __expf(acc[mi][ni][2] + sb[ni * 4 + 2]);
      s3 += __expf(acc[mi][ni][3] + sb[ni * 4 + 3]);
    }
    float s = (s0 + s1) + (s2 + s3);
    s += __shfl_xor(s, 16, 64);
    s += __shfl_xor(s, 32, 64);
    if (hi == 0) atomicAdd(&SUM[row], s);
  }
}

// ---------------- 4-segment parallel fo-pool scan ----------------
// c_t = f_t c + (1-f_t) z_t is affine in c: over segment s (64 steps),
// c_out = A_s * c_in + B_s with A_s = prod f, B_s = zero-init scan.
// Pass 1: each (b,d,s) computes (A_s, B_s). Pass 2: compose c_init
// (<=3 fma), re-scan writing h. Serial length 256 -> 64+64; waves x4.
__global__ __launch_bounds__(64) void scan_seg1(const ushort* __restrict__ PRE,
                                                float* __restrict__ AS,
                                                float* __restrict__ BS) {
  int idx = blockIdx.x * 64 + threadIdx.x;    // 65536 = 4 * 32 * 512
  int s = idx >> 14, rem = idx & 16383;
  int b = rem >> 9, d = rem & 511;
  const ushort* p = PRE + (size_t)b * TT * G3 + (size_t)(s * 64) * G3 + d;
  float a = 1.f, c = 0.f;
  for (int t0 = 0; t0 < 64; t0 += 8) {
    float pz[8], pf[8];
#pragma unroll
    for (int i = 0; i < 8; ++i) {
      const ushort* q = p + (size_t)(t0 + i) * G3;
      pz[i] = bf2f(q[0]); pf[i] = bf2f(q[512]);
    }
#pragma unroll
    for (int i = 0; i < 8; ++i) {
      float z = 2.f / (1.f + __expf(-2.f * pz[i])) - 1.f;
      float f = 1.f / (1.f + __expf(-pf[i]));
      c = f * c + (1.f - f) * z;
      a *= f;
    }
  }
  AS[idx] = a; BS[idx] = c;
}

__global__ __launch_bounds__(64) void scan_seg2(const ushort* __restrict__ PRE,
                                                const float* __restrict__ AS,
                                                const float* __restrict__ BS,
                                                unsigned char* __restrict__ OUT8,
                                                int mode) {
  int idx = blockIdx.x * 64 + threadIdx.x;
  int s = idx >> 14, rem = idx & 16383;
  int b = rem >> 9, d = rem & 511;
  float c = 0.f;
  for (int u = 0; u < s; ++u)               // wave-uniform s -> no divergence
    c = AS[u * 16384 + rem] * c + BS[u * 16384 + rem];
  const ushort* p = PRE + (size_t)b * TT * G3 + d;
  int poff = physk(d);
  for (int t0 = s * 64; t0 < s * 64 + 64; t0 += 8) {
    float pz[8], pf[8], po[8];
#pragma unroll
    for (int i = 0; i < 8; ++i) {
      const ushort* q = p + (size_t)(t0 + i) * G3;
      pz[i] = bf2f(q[0]); pf[i] = bf2f(q[512]); po[i] = bf2f(q[1024]);
    }
#pragma unroll
    for (int i = 0; i < 8; ++i) {
      float z = 2.f / (1.f + __expf(-2.f * pz[i])) - 1.f;
      float f = 1.f / (1.f + __expf(-pf[i]));
      float o = 1.f / (1.f + __expf(-po[i]));
      c = f * c + (1.f - f) * z;
      float h = o * c;
      int tt = t0 + i;
      size_t r = (size_t)b * TT + tt;
      unsigned char hb = f2e4m3(h);
      if (mode == 0) {
        OUT8[r * 1024 + 512 + poff] = hb;
        if (tt < TT - 1) OUT8[(r + 1) * 1024 + poff] = hb;
        if (tt == 0)     OUT8[r * 1024 + poff] = 0;
      } else {
        OUT8[r * 512 + poff] = hb;
      }
    }
  }
}

// ---------------- helpers ----------------
__global__ void zero_kernel(float* __restrict__ p, int n) {
  int i = blockIdx.x * 256 + threadIdx.x;
  if (i < n) p[i] = 0.f;
}

__global__ __launch_bounds__(256) void cost_kernel(const float* __restrict__ sumexp,
                                                   const float* __restrict__ tgl,
                                                   float* __restrict__ out) {
  int t = threadIdx.x;
  float s = 0.f;
  for (int r = t; r < R; r += 256) s += logf(sumexp[r]) - tgl[r];
#pragma unroll
  for (int m = 1; m < 64; m <<= 1) s += __shfl_xor(s, m, 64);
  __shared__ float red[4];
  int wave = t >> 6, lane = t & 63;
  if (lane == 0) red[wave] = s;
  __syncthreads();
  if (t == 0) out[0] = (red[0] + red[1] + red[2] + red[3]) / (float)R;
}

extern "C" void kernel_launch(void* const* d_in, const int* in_sizes, int n_in,
                              void* d_out, int out_size, void* d_ws, size_t ws_size,
                              hipStream_t stream) {
  const int*   tok = (const int*)d_in[0];
  const int*   tgt = (const int*)d_in[1];
  const float* emb = (const float*)d_in[2];
  const float* Wz0 = (const float*)d_in[3];  const float* bz0 = (const float*)d_in[4];
  const float* Wf0 = (const float*)d_in[5];  const float* bf0 = (const float*)d_in[6];
  const float* Wo0 = (const float*)d_in[7];  const float* bo0 = (const float*)d_in[8];
  const float* Wz1 = (const float*)d_in[9];  const float* bz1 = (const float*)d_in[10];
  const float* Wf1 = (const float*)d_in[11]; const float* bf1 = (const float*)d_in[12];
  const float* Wo1 = (const float*)d_in[13]; const float* bo1 = (const float*)d_in[14];
  const float* SW  = (const float*)d_in[15]; const float* SB  = (const float*)d_in[16];
  float* out = (float*)d_out;

  // workspace layout (bytes), total ~49.9 MB:
  char* base = (char*)d_ws;
  unsigned char* XA8 = (unsigned char*)(base);             //  8,388,608 [R][1024] fp8 phys-K
  unsigned char* YA8 = (unsigned char*)(base + 8388608);   //  8,388,608 [R][1024] fp8 phys-K
  ushort*        PRE = (ushort*)(base + 16777216);         // 25,165,824 [R][1536] bf16
  unsigned char* H8  = (unsigned char*)(base + 41943040);  //  4,194,304 [R][512]  fp8 phys-K
  unsigned char* WT80 = (unsigned char*)(base + 46137344); //  1,572,864 [1536][1024] fp8 phys-K
  unsigned char* WT81 = (unsigned char*)(base + 47710208); //  1,572,864
  float*         BC0 = (float*)(base + 49283072);          //  6,144
  float*         BC1 = (float*)(base + 49289216);          //  6,144
  float*         SUM = (float*)(base + 49295360);          //  32,768
  float*         TGL = (float*)(base + 49328128);          //  32,768
  float*         AS  = (float*)(base + 49360896);          //  262,144 (4*16384 f32)
  float*         BS  = (float*)(base + 49623040);          //  262,144
  unsigned char* SW8T = (unsigned char*)(base);            // 16,384,000 — aliases XA8+YA8 (dead by then)

  embed_kernel<<<R * 128 / 256, 256, 0, stream>>>(tok, (const float4*)emb, XA8);
  wconv<<<dim3(8, 8, 6), 256, 0, stream>>>(Wz0, Wf0, Wo0, WT80);
  wconv<<<dim3(8, 8, 6), 256, 0, stream>>>(Wz1, Wf1, Wo1, WT81);
  bcat_kernel<<<12, 256, 0, stream>>>(bz0, bf0, bo0, bz1, bf1, bo1, BC0, BC1);

  gemm_pre_fp8<<<dim3(32, 12), 256, 0, stream>>>(XA8, WT80, BC0, PRE);
  scan_seg1<<<1024, 64, 0, stream>>>(PRE, AS, BS);
  scan_seg2<<<1024, 64, 0, stream>>>(PRE, AS, BS, YA8, 0);
  gemm_pre_fp8<<<dim3(32, 12), 256, 0, stream>>>(YA8, WT81, BC1, PRE);
  scan_seg1<<<1024, 64, 0, stream>>>(PRE, AS, BS);
  scan_seg2<<<1024, 64, 0, stream>>>(PRE, AS, BS, H8, 1);

  // SW8T aliases XA8/YA8 — both dead after the second gemm_pre_fp8
  swconv<<<dim3(8, 500), 256, 0, stream>>>(SW, SW8T);
  zero_kernel<<<32, 256, 0, stream>>>(SUM, R);
  tgl_kernel<<<R / 4, 256, 0, stream>>>(H8, SW8T, SB, tgt, TGL);
  gemm_lse_fp8<<<dim3(32, 250), 256, 0, stream>>>(H8, SW8T, SB, SUM);
  cost_kernel<<<1, 256, 0, stream>>>(SUM, TGL, out);
}

// Round 15
// 304.379 us; speedup vs baseline: 2.6718x; 1.0618x over previous
//
#include <hip/hip_runtime.h>
#include <hip/hip_bf16.h>
#include <math.h>

// Problem constants (B=32, T=256, V=32000, D=512)
#define R   8192    // B*T rows
#define TT  256
#define D   512
#define V   32000
#define G3  1536    // 3*D (z|f|o)

typedef __attribute__((ext_vector_type(8))) short bf16x8;
typedef __attribute__((ext_vector_type(4))) float f32x4;
typedef __attribute__((ext_vector_type(4))) int   i32x4;
typedef __attribute__((ext_vector_type(8))) int   i32x8;

__device__ __forceinline__ float bf2f(ushort u) {
  union { unsigned int i; float f; } x; x.i = ((unsigned int)u) << 16; return x.f;
}
__device__ __forceinline__ ushort f2bf(float f) {   // RNE
  union { float f; unsigned int i; } x; x.f = f;
  unsigned int r = x.i + 0x7fffu + ((x.i >> 16) & 1u);
  return (ushort)(r >> 16);
}

// f32 -> OCP e4m3fn, round-nearest-even, clamp to 448. Exact integer-grid method.
__device__ __forceinline__ unsigned char f2e4m3(float f) {
  unsigned char s = (__float_as_uint(f) >> 31) ? 0x80 : 0x00;
  float a = fabsf(f);
  if (!(a < 448.f)) return s | 0x7e;       // clamp (no NaN/overflow in our data)
  if (a == 0.f) return s;
  int ef; frexpf(a, &ef);                  // a = m*2^ef, m in [0.5,1)
  int E = ef - 1;                          // a = (2m)*2^E
  if (E < -6) E = -6;                      // denormal grid
  float ulp = ldexpf(1.f, E - 3);
  int qi = (int)rintf(a / ulp);            // exact scale (pow2), RNE, qi in [0,16]
  if (qi >= 16) { E += 1; qi = 8; }
  unsigned char bits = (qi < 8) ? (unsigned char)qi
                                : (unsigned char)(((E + 7) << 3) | (qi - 8));
  return s | bits;
}

// OCP e4m3fn -> f32 (exact decode; 0x7f NaN never produced by f2e4m3)
__device__ __forceinline__ float e4m3f(unsigned char b) {
  int e = (b >> 3) & 15, m = b & 7;
  float v;
  if (e == 0) v = (float)m * 0.001953125f;            // m * 2^-9
  else { union { unsigned u; float f; } x;
         x.u = ((unsigned)(e + 120) << 23) | ((unsigned)m << 20); v = x.f; }
  return (b & 0x80) ? -v : v;
}

// phys-K transpose within each 128-elem block: element k stored at
// poff(k) = (k&~127) | h*32 | ks*8 | j  where k = (k&~127)+ks*32+h*8+j.
__device__ __forceinline__ int physk(int d) {
  return (d & ~127) | (((d >> 3) & 3) << 5) | (((d >> 5) & 3) << 3) | (d & 7);
}

__device__ __forceinline__ void gload16(const void* g, void* l) {
  __builtin_amdgcn_global_load_lds((const __attribute__((address_space(1))) void*)g,
                                   (__attribute__((address_space(3))) void*)l, 16, 0, 0);
}

// ---------------- embedding gather -> XA8 fp8 phys-K [R][1024] = [x_prev | x] ----------------
__global__ __launch_bounds__(256) void embed_kernel(const int* __restrict__ tok,
                                                    const float4* __restrict__ emb,
                                                    unsigned char* __restrict__ XA8) {
  int idx = blockIdx.x * 256 + threadIdx.x;   // over R*128 float4s
  int r = idx >> 7, d4 = idx & 127;
  float4 v = emb[(size_t)tok[r] * 128 + d4];
  uchar4 h8;
  h8.x = f2e4m3(v.x); h8.y = f2e4m3(v.y); h8.z = f2e4m3(v.z); h8.w = f2e4m3(v.w);
  int pp = physk(d4 * 4);                     // aligned-4 contiguous run
  *(uchar4*)(XA8 + (size_t)r * 1024 + 512 + pp) = h8;          // x part
  int t = r & (TT - 1);
  if (t < TT - 1) *(uchar4*)(XA8 + (size_t)(r + 1) * 1024 + pp) = h8;  // next row x_prev
  if (t == 0) { uchar4 z = {0, 0, 0, 0}; *(uchar4*)(XA8 + (size_t)r * 1024 + pp) = z; }
}

// ---------------- coalesced fp8 phys-K transpose-convert helper ----------------
__device__ __forceinline__ void tconv_write(const float (*tile)[65],
                                            unsigned char* __restrict__ dstrow0,
                                            size_t ldb, int k0, int t) {
  int nn = t & 63, h = t >> 6;
  union { unsigned char c[16]; uint4 q; } u;
#pragma unroll
  for (int ksl = 0; ksl < 2; ++ksl)
#pragma unroll
    for (int j = 0; j < 8; ++j)
      u.c[ksl * 8 + j] = f2e4m3(tile[ksl * 32 + h * 8 + j][nn]);
  unsigned char* dst = dstrow0 + (size_t)nn * ldb + (k0 & ~127) + h * 32 + ((k0 & 64) ? 16 : 0);
  *(uint4*)dst = u.q;
}

// ---------------- weight transpose+convert (BOTH layers): WT8[1536][1024] fp8 phys-K ----------------
// z in 0..11: layer = z/6, zz = z%6, g = zz>>1, i = zz&1.
__global__ __launch_bounds__(256) void wconv(const float* __restrict__ Wz0,
                                             const float* __restrict__ Wf0,
                                             const float* __restrict__ Wo0,
                                             const float* __restrict__ Wz1,
                                             const float* __restrict__ Wf1,
                                             const float* __restrict__ Wo1,
                                             unsigned char* __restrict__ WT80,
                                             unsigned char* __restrict__ WT81) {
  __shared__ float tile[64][65];
  int z = blockIdx.z;
  int layer = z >= 6 ? 1 : 0, zz = z - 6 * layer;
  int g = zz >> 1, i = zz & 1;
  const float* src = layer == 0 ? (g == 0 ? Wz0 : (g == 1 ? Wf0 : Wo0))
                                : (g == 0 ? Wz1 : (g == 1 ? Wf1 : Wo1));
  unsigned char* WT8 = layer == 0 ? WT80 : WT81;
  src += (size_t)i * D * D;
  int d0 = blockIdx.x * 64, e0 = blockIdx.y * 64;
  int t = threadIdx.x, c = t & 63, rq = t >> 6;
#pragma unroll
  for (int p = 0; p < 16; ++p) {
    int dd = p * 4 + rq;
    tile[dd][c] = src[(size_t)(d0 + dd) * D + e0 + c];   // [k=d][n=e]
  }
  __syncthreads();
  tconv_write(tile, WT8 + (size_t)(g * D + e0) * 1024, 1024, i * 512 + d0, t);
}

// ---------------- softmax weight transpose+convert: SW8T[32000][512] fp8 phys-K ----------------
__global__ __launch_bounds__(256) void swconv(const float* __restrict__ SW,
                                              unsigned char* __restrict__ SWT) {
  __shared__ float tile[64][65];
  int k0 = blockIdx.x * 64, n0 = blockIdx.y * 64;
  int t = threadIdx.x, c = t & 63, rq = t >> 6;
#pragma unroll
  for (int p = 0; p < 16; ++p) {
    int kk = p * 4 + rq;
    tile[kk][c] = SW[(size_t)(k0 + kk) * V + n0 + c];
  }
  __syncthreads();
  tconv_write(tile, SWT + (size_t)n0 * 512, 512, k0, t);
}

// ---------------- MX-fp8 256x128 GEMM core (VERIFIED r14) ----------------
// 256 thr / 4 waves; wave tile 128x64. BK=128, LDS = A 32KB + B 16KB = 48KB.
// Swapped MFMA (mfma(b8,a8)): C row = lane&15 (lane-local), C col = (lane>>4)*4+j.
template<int LD, int NKT>
__device__ __forceinline__ void mx_core256(const unsigned char* __restrict__ A,
                                           const unsigned char* __restrict__ B,
                                           int row0, int col0, char* lds,
                                           f32x4 acc[8][4]) {
  char* As = lds;            // 256 rows x 128B
  char* Bs = lds + 32768;    // 128 rows x 128B
  const int t = threadIdx.x, lane = t & 63, w = t >> 6;
  const int wm = w >> 1, wn = w & 1;
  const int lo = lane & 15, hi = lane >> 4;
  const int gr = t >> 3;             // row within 32-row issue
  const int ss = (t & 7) ^ (gr & 7); // inverse-swizzled source slot
  const int x  = lo & 7;             // frag-read row swizzle

#pragma unroll 1
  for (int kt = 0; kt < NKT; ++kt) {
    const int k0 = kt * 128;
#pragma unroll
    for (int i = 0; i < 8; ++i)
      gload16(A + (size_t)(row0 + i * 32 + gr) * LD + k0 + ss * 16,
              As + i * 4096 + t * 16);
#pragma unroll
    for (int i = 0; i < 4; ++i)
      gload16(B + (size_t)(col0 + i * 32 + gr) * LD + k0 + ss * 16,
              Bs + i * 4096 + t * 16);
    __syncthreads();
    i32x8 b8[4];
#pragma unroll
    for (int ni = 0; ni < 4; ++ni) {
      const char* rb = Bs + (wn * 64 + ni * 16 + lo) * 128;
      union { i32x8 v8; i32x4 v4[2]; } u;
      u.v4[0] = *(const i32x4*)(rb + ((hi * 2 + 0) ^ x) * 16);
      u.v4[1] = *(const i32x4*)(rb + ((hi * 2 + 1) ^ x) * 16);
      b8[ni] = u.v8;
    }
#pragma unroll
    for (int mi = 0; mi < 8; ++mi) {
      const char* rb = As + (wm * 128 + mi * 16 + lo) * 128;
      union { i32x8 v8; i32x4 v4[2]; } u;
      u.v4[0] = *(const i32x4*)(rb + ((hi * 2 + 0) ^ x) * 16);
      u.v4[1] = *(const i32x4*)(rb + ((hi * 2 + 1) ^ x) * 16);
      i32x8 a8 = u.v8;
#pragma unroll
      for (int ni = 0; ni < 4; ++ni)
        acc[mi][ni] = __builtin_amdgcn_mfma_scale_f32_16x16x128_f8f6f4(
            b8[ni], a8, acc[mi][ni], 0, 0, 0, 0x7F, 0, 0x7F);
    }
    __syncthreads();
  }
}

// ---------------- QRNN pre-activation GEMM (8192x1536x1024, MX-fp8, 256x128, fused bias) ----------------
__global__ __launch_bounds__(256, 2) void gemm_pre_fp8(const unsigned char* __restrict__ A,
                                                       const unsigned char* __restrict__ B,
                                                       const float* __restrict__ bz,
                                                       const float* __restrict__ bf,
                                                       const float* __restrict__ bo,
                                                       ushort* __restrict__ PRE) {
  __shared__ char lds[49152];
  const int t = threadIdx.x, lane = t & 63, w = t >> 6;
  const int wm = w >> 1, wn = w & 1;
  const int lo = lane & 15, hi = lane >> 4;
  const int row0 = blockIdx.x * 256, col0 = blockIdx.y * 128;
  const int g = col0 >> 9;                       // gate uniform per block (128 | 512)
  const float* bg = (g == 0) ? bz : (g == 1 ? bf : bo);

  f32x4 acc[8][4];
#pragma unroll
  for (int i = 0; i < 8; ++i)
#pragma unroll
    for (int j = 0; j < 4; ++j) { f32x4 z = {0.f,0.f,0.f,0.f}; acc[i][j] = z; }

  mx_core256<1024, 8>(A, B, row0, col0, lds, acc);

  // swapped layout: row = +lo (lane-local), col = colb + j -> ushort4 stores
#pragma unroll
  for (int mi = 0; mi < 8; ++mi) {
    const int row = row0 + wm * 128 + mi * 16 + lo;
#pragma unroll
    for (int ni = 0; ni < 4; ++ni) {
      const int colb = col0 + wn * 64 + ni * 16 + hi * 4;
      const int eb = colb & 511;
      ushort4 v;
      v.x = f2bf(acc[mi][ni][0] + bg[eb + 0]);
      v.y = f2bf(acc[mi][ni][1] + bg[eb + 1]);
      v.z = f2bf(acc[mi][ni][2] + bg[eb + 2]);
      v.w = f2bf(acc[mi][ni][3] + bg[eb + 3]);
      *(ushort4*)(PRE + (size_t)row * G3 + colb) = v;
    }
  }
}

// ---------------- target-logit kernel (+ SUM zero): TGL[row] = dot(H8[row], SW8T[tgt]) + SB[tgt] ----------------
__global__ __launch_bounds__(256) void tgl_kernel(const unsigned char* __restrict__ H8,
                                                  const unsigned char* __restrict__ SWT,
                                                  const float* __restrict__ SB,
                                                  const int* __restrict__ tgt,
                                                  float* __restrict__ TGL,
                                                  float* __restrict__ SUM) {
  int wid  = (blockIdx.x * 256 + threadIdx.x) >> 6;   // one wave per row
  int lane = threadIdx.x & 63;
  if (lane == 0) SUM[wid] = 0.f;                      // zero before lse's atomics
  int tg = tgt[wid];
  uint2 hv = *(const uint2*)(H8  + (size_t)wid * 512 + lane * 8);
  uint2 wv = *(const uint2*)(SWT + (size_t)tg  * 512 + lane * 8);
  float s = 0.f;
#pragma unroll
  for (int k = 0; k < 4; ++k)
    s += e4m3f((hv.x >> (8 * k)) & 255) * e4m3f((wv.x >> (8 * k)) & 255);
#pragma unroll
  for (int k = 0; k < 4; ++k)
    s += e4m3f((hv.y >> (8 * k)) & 255) * e4m3f((wv.y >> (8 * k)) & 255);
#pragma unroll
  for (int m = 1; m < 64; m <<= 1) s += __shfl_xor(s, m, 64);
  if (lane == 0) TGL[wid] = s + SB[tg];
}

// ---------------- MX-fp8 logits GEMM + fused exp-sum (256x128, slim epilogue) — r14 exact ----------------
__global__ __launch_bounds__(256, 2) void gemm_lse_fp8(const unsigned char* __restrict__ A,
                                                       const unsigned char* __restrict__ B,
                                                       const float* __restrict__ SB,
                                                       float* __restrict__ SUM) {
  __shared__ char lds[49152];
  const int t = threadIdx.x, lane = t & 63, w = t >> 6;
  const int wm = w >> 1, wn = w & 1;
  const int lo = lane & 15, hi = lane >> 4;
  const int row0 = blockIdx.x * 256, col0 = blockIdx.y * 128;

  // preload bias (uniform per thread) before the K-loop: hides latency
  float sb[16];
#pragma unroll
  for (int ni = 0; ni < 4; ++ni)
#pragma unroll
    for (int j = 0; j < 4; ++j)
      sb[ni * 4 + j] = SB[col0 + wn * 64 + ni * 16 + hi * 4 + j];

  f32x4 acc[8][4];
#pragma unroll
  for (int i = 0; i < 8; ++i)
#pragma unroll
    for (int j = 0; j < 4; ++j) { f32x4 z = {0.f,0.f,0.f,0.f}; acc[i][j] = z; }

  mx_core256<512, 4>(A, B, row0, col0, lds, acc);

  // epilogue (swapped layout): out_row = row0+wm*128+mi*16+lo (lane-local).
  // 4 independent partial sums break the dependent add chain.
#pragma unroll
  for (int mi = 0; mi < 8; ++mi) {
    const int row = row0 + wm * 128 + mi * 16 + lo;
    float s0 = 0.f, s1 = 0.f, s2 = 0.f, s3 = 0.f;
#pragma unroll
    for (int ni = 0; ni < 4; ++ni) {
      s0 += __expf(acc[mi][ni][0] + sb[ni * 4 + 0]);
      s1 += __expf(acc[mi][ni][1] + sb[ni * 4 + 1]);
      s2 += __expf(acc[mi][ni][2] + sb[ni * 4 + 2]);
      s3 += __expf(acc[mi][ni][3] + sb[ni * 4 + 3]);
    }
    float s = (s0 + s1) + (s2 + s3);
    s += __shfl_xor(s, 16, 64);
    s += __shfl_xor(s, 32, 64);
    if (hi == 0) atomicAdd(&SUM[row], s);
  }
}

// ---------------- fused 4-segment parallel fo-pool scan ----------------
// Block = (64 d-values) x (4 segments); grid = (b 32, d-chunk 8) = 256 blocks.
// Phase 1: per-segment (A,B) = (prod f, zero-init scan) over 64 steps (z,f).
// LDS exchange; compose c_init (s wave-uniform, <=3 fma). Phase 2: re-scan
// segment from c_init, writing h (fp8 phys-K out).
__global__ __launch_bounds__(256) void scan_fused(const ushort* __restrict__ PRE,
                                                  unsigned char* __restrict__ OUT8,
                                                  int mode) {
  __shared__ float Als[4][64], Bls[4][64];
  const int b = blockIdx.x, dc = blockIdx.y;
  const int tid = threadIdx.x, dl = tid & 63, s = tid >> 6;   // s wave-uniform
  const int d = dc * 64 + dl;
  const ushort* p  = PRE + (size_t)b * TT * G3 + d;
  const ushort* ps = p + (size_t)(s * 64) * G3;

  // phase 1: segment transfer function
  float a = 1.f, c = 0.f;
  for (int t0 = 0; t0 < 64; t0 += 8) {
    float pz[8], pf[8];
#pragma unroll
    for (int i = 0; i < 8; ++i) {
      const ushort* q = ps + (size_t)(t0 + i) * G3;
      pz[i] = bf2f(q[0]); pf[i] = bf2f(q[512]);
    }
#pragma unroll
    for (int i = 0; i < 8; ++i) {
      float z = 2.f / (1.f + __expf(-2.f * pz[i])) - 1.f;
      float f = 1.f / (1.f + __expf(-pf[i]));
      c = f * c + (1.f - f) * z;
      a *= f;
    }
  }
  Als[s][dl] = a; Bls[s][dl] = c;
  __syncthreads();
  float cc = 0.f;
  for (int u = 0; u < s; ++u)          // wave-uniform bound, no divergence
    cc = Als[u][dl] * cc + Bls[u][dl];

  // phase 2: re-scan writing h
  const int poff = physk(d);
  for (int t0 = s * 64; t0 < s * 64 + 64; t0 += 8) {
    float pz[8], pf[8], po[8];
#pragma unroll
    for (int i = 0; i < 8; ++i) {
      const ushort* q = p + (size_t)(t0 + i) * G3;
      pz[i] = bf2f(q[0]); pf[i] = bf2f(q[512]); po[i] = bf2f(q[1024]);
    }
#pragma unroll
    for (int i = 0; i < 8; ++i) {
      float z = 2.f / (1.f + __expf(-2.f * pz[i])) - 1.f;
      float f = 1.f / (1.f + __expf(-pf[i]));
      float o = 1.f / (1.f + __expf(-po[i]));
      cc = f * cc + (1.f - f) * z;
      float h = o * cc;
      int tt = t0 + i;
      size_t r = (size_t)b * TT + tt;
      unsigned char hb = f2e4m3(h);
      if (mode == 0) {
        OUT8[r * 1024 + 512 + poff] = hb;
        if (tt < TT - 1) OUT8[(r + 1) * 1024 + poff] = hb;
        if (tt == 0)     OUT8[r * 1024 + poff] = 0;
      } else {
        OUT8[r * 512 + poff] = hb;
      }
    }
  }
}

// ---------------- final cost ----------------
__global__ __launch_bounds__(256) void cost_kernel(const float* __restrict__ sumexp,
                                                   const float* __restrict__ tgl,
                                                   float* __restrict__ out) {
  int t = threadIdx.x;
  float s = 0.f;
  for (int r = t; r < R; r += 256) s += logf(sumexp[r]) - tgl[r];
#pragma unroll
  for (int m = 1; m < 64; m <<= 1) s += __shfl_xor(s, m, 64);
  __shared__ float red[4];
  int wave = t >> 6, lane = t & 63;
  if (lane == 0) red[wave] = s;
  __syncthreads();
  if (t == 0) out[0] = (red[0] + red[1] + red[2] + red[3]) / (float)R;
}

extern "C" void kernel_launch(void* const* d_in, const int* in_sizes, int n_in,
                              void* d_out, int out_size, void* d_ws, size_t ws_size,
                              hipStream_t stream) {
  const int*   tok = (const int*)d_in[0];
  const int*   tgt = (const int*)d_in[1];
  const float* emb = (const float*)d_in[2];
  const float* Wz0 = (const float*)d_in[3];  const float* bz0 = (const float*)d_in[4];
  const float* Wf0 = (const float*)d_in[5];  const float* bf0 = (const float*)d_in[6];
  const float* Wo0 = (const float*)d_in[7];  const float* bo0 = (const float*)d_in[8];
  const float* Wz1 = (const float*)d_in[9];  const float* bz1 = (const float*)d_in[10];
  const float* Wf1 = (const float*)d_in[11]; const float* bf1 = (const float*)d_in[12];
  const float* Wo1 = (const float*)d_in[13]; const float* bo1 = (const float*)d_in[14];
  const float* SW  = (const float*)d_in[15]; const float* SB  = (const float*)d_in[16];
  float* out = (float*)d_out;

  // workspace layout (bytes), total ~49.4 MB:
  char* base = (char*)d_ws;
  unsigned char* XA8 = (unsigned char*)(base);             //  8,388,608 [R][1024] fp8 phys-K
  unsigned char* YA8 = (unsigned char*)(base + 8388608);   //  8,388,608 [R][1024] fp8 phys-K
  ushort*        PRE = (ushort*)(base + 16777216);         // 25,165,824 [R][1536] bf16
  unsigned char* H8  = (unsigned char*)(base + 41943040);  //  4,194,304 [R][512]  fp8 phys-K
  unsigned char* WT80 = (unsigned char*)(base + 46137344); //  1,572,864 [1536][1024] fp8 phys-K
  unsigned char* WT81 = (unsigned char*)(base + 47710208); //  1,572,864
  float*         SUM = (float*)(base + 49295360);          //  32,768
  float*         TGL = (float*)(base + 49328128);          //  32,768
  unsigned char* SW8T = (unsigned char*)(base);            // 16,384,000 — aliases XA8+YA8 (dead by then)

  embed_kernel<<<R * 128 / 256, 256, 0, stream>>>(tok, (const float4*)emb, XA8);
  wconv<<<dim3(8, 8, 12), 256, 0, stream>>>(Wz0, Wf0, Wo0, Wz1, Wf1, Wo1, WT80, WT81);

  gemm_pre_fp8<<<dim3(32, 12), 256, 0, stream>>>(XA8, WT80, bz0, bf0, bo0, PRE);
  scan_fused<<<dim3(32, 8), 256, 0, stream>>>(PRE, YA8, 0);
  gemm_pre_fp8<<<dim3(32, 12), 256, 0, stream>>>(YA8, WT81, bz1, bf1, bo1, PRE);
  scan_fused<<<dim3(32, 8), 256, 0, stream>>>(PRE, H8, 1);

  // SW8T aliases XA8/YA8 — both dead after the second gemm_pre_fp8
  swconv<<<dim3(8, 500), 256, 0, stream>>>(SW, SW8T);
  tgl_kernel<<<R / 4, 256, 0, stream>>>(H8, SW8T, SB, tgt, TGL, SUM);
  gemm_lse_fp8<<<dim3(32, 250), 256, 0, stream>>>(H8, SW8T, SB, SUM);
  cost_kernel<<<1, 256, 0, stream>>>(SUM, TGL, out);
}

// Round 16
// 283.976 us; speedup vs baseline: 2.8637x; 1.0718x over previous
//
#include <hip/hip_runtime.h>
#include <hip/hip_bf16.h>
#include <math.h>

// Problem constants (B=32, T=256, V=32000, D=512)
#define R   8192    // B*T rows
#define TT  256
#define D   512
#define V   32000
#define G3  1536    // 3*D (z|f|o)

typedef __attribute__((ext_vector_type(8))) short bf16x8;
typedef __attribute__((ext_vector_type(4))) float f32x4;
typedef __attribute__((ext_vector_type(4))) int   i32x4;
typedef __attribute__((ext_vector_type(8))) int   i32x8;

__device__ __forceinline__ float bf2f(ushort u) {
  union { unsigned int i; float f; } x; x.i = ((unsigned int)u) << 16; return x.f;
}
__device__ __forceinline__ ushort f2bf(float f) {   // RNE
  union { float f; unsigned int i; } x; x.f = f;
  unsigned int r = x.i + 0x7fffu + ((x.i >> 16) & 1u);
  return (ushort)(r >> 16);
}

// f32 -> OCP e4m3fn, round-nearest-even, clamp to 448. Exact integer-grid method.
__device__ __forceinline__ unsigned char f2e4m3(float f) {
  unsigned char s = (__float_as_uint(f) >> 31) ? 0x80 : 0x00;
  float a = fabsf(f);
  if (!(a < 448.f)) return s | 0x7e;       // clamp (no NaN/overflow in our data)
  if (a == 0.f) return s;
  int ef; frexpf(a, &ef);                  // a = m*2^ef, m in [0.5,1)
  int E = ef - 1;                          // a = (2m)*2^E
  if (E < -6) E = -6;                      // denormal grid
  float ulp = ldexpf(1.f, E - 3);
  int qi = (int)rintf(a / ulp);            // exact scale (pow2), RNE, qi in [0,16]
  if (qi >= 16) { E += 1; qi = 8; }
  unsigned char bits = (qi < 8) ? (unsigned char)qi
                                : (unsigned char)(((E + 7) << 3) | (qi - 8));
  return s | bits;
}

// OCP e4m3fn -> f32 (exact decode; 0x7f NaN never produced by f2e4m3)
__device__ __forceinline__ float e4m3f(unsigned char b) {
  int e = (b >> 3) & 15, m = b & 7;
  float v;
  if (e == 0) v = (float)m * 0.001953125f;            // m * 2^-9
  else { union { unsigned u; float f; } x;
         x.u = ((unsigned)(e + 120) << 23) | ((unsigned)m << 20); v = x.f; }
  return (b & 0x80) ? -v : v;
}

// f32 (pre-scaled) -> fp4 e2m1 code, RNE to grid {0,.5,1,1.5,2,3,4,6}, clamp 6.
__device__ __forceinline__ unsigned char f2e2m1(float v) {
  unsigned char s = (v < 0.f) ? 8 : 0;
  float a = fabsf(v);
  unsigned char q;
  if      (a < 0.25f) q = 0;
  else if (a < 0.75f) q = 1;
  else if (a < 1.25f) q = 2;
  else if (a < 1.75f) q = 3;
  else if (a < 2.5f)  q = 4;
  else if (a < 3.5f)  q = 5;
  else if (a < 5.0f)  q = 6;
  else                q = 7;
  return s | q;
}

// phys-K transpose within each 128-elem block: element k stored at
// poff(k) = (k&~127) | h*32 | ks*8 | j  where k = (k&~127)+ks*32+h*8+j.
// (byte units for fp8, nibble units for fp4 — same index function.)
__device__ __forceinline__ int physk(int d) {
  return (d & ~127) | (((d >> 3) & 3) << 5) | (((d >> 5) & 3) << 3) | (d & 7);
}

__device__ __forceinline__ void gload16(const void* g, void* l) {
  __builtin_amdgcn_global_load_lds((const __attribute__((address_space(1))) void*)g,
                                   (__attribute__((address_space(3))) void*)l, 16, 0, 0);
}

// ---------------- embedding gather -> XA8 fp8 phys-K [R][1024] = [x_prev | x] ----------------
__global__ __launch_bounds__(256) void embed_kernel(const int* __restrict__ tok,
                                                    const float4* __restrict__ emb,
                                                    unsigned char* __restrict__ XA8) {
  int idx = blockIdx.x * 256 + threadIdx.x;   // over R*128 float4s
  int r = idx >> 7, d4 = idx & 127;
  float4 v = emb[(size_t)tok[r] * 128 + d4];
  uchar4 h8;
  h8.x = f2e4m3(v.x); h8.y = f2e4m3(v.y); h8.z = f2e4m3(v.z); h8.w = f2e4m3(v.w);
  int pp = physk(d4 * 4);                     // aligned-4 contiguous run
  *(uchar4*)(XA8 + (size_t)r * 1024 + 512 + pp) = h8;          // x part
  int t = r & (TT - 1);
  if (t < TT - 1) *(uchar4*)(XA8 + (size_t)(r + 1) * 1024 + pp) = h8;  // next row x_prev
  if (t == 0) { uchar4 z = {0, 0, 0, 0}; *(uchar4*)(XA8 + (size_t)r * 1024 + pp) = z; }
}

// ---------------- coalesced fp8 phys-K transpose-convert helper ----------------
__device__ __forceinline__ void tconv_write(const float (*tile)[65],
                                            unsigned char* __restrict__ dstrow0,
                                            size_t ldb, int k0, int t) {
  int nn = t & 63, h = t >> 6;
  union { unsigned char c[16]; uint4 q; } u;
#pragma unroll
  for (int ksl = 0; ksl < 2; ++ksl)
#pragma unroll
    for (int j = 0; j < 8; ++j)
      u.c[ksl * 8 + j] = f2e4m3(tile[ksl * 32 + h * 8 + j][nn]);
  unsigned char* dst = dstrow0 + (size_t)nn * ldb + (k0 & ~127) + h * 32 + ((k0 & 64) ? 16 : 0);
  *(uint4*)dst = u.q;
}

// fp4 variant: same phys map in NIBBLE units; 16 elems -> 8 bytes (low nibble = even j).
__device__ __forceinline__ void tconv4_write(const float (*tile)[65],
                                             unsigned char* __restrict__ dstrow0,
                                             size_t ldb4, int k0, int t, float scale) {
  int nn = t & 63, h = t >> 6;
  union { unsigned char c[8]; uint2 q; } u;
#pragma unroll
  for (int ksl = 0; ksl < 2; ++ksl)
#pragma unroll
    for (int jp = 0; jp < 4; ++jp) {
      unsigned char l4 = f2e2m1(tile[ksl * 32 + h * 8 + jp * 2    ][nn] * scale);
      unsigned char h4 = f2e2m1(tile[ksl * 32 + h * 8 + jp * 2 + 1][nn] * scale);
      u.c[ksl * 4 + jp] = l4 | (h4 << 4);
    }
  unsigned char* dst = dstrow0 + (size_t)nn * ldb4 + ((k0 & ~127) >> 1) + h * 16 + ((k0 & 64) ? 8 : 0);
  *(uint2*)dst = u.q;
}

// ---------------- weight transpose+convert (BOTH layers): WT8[1536][1024] fp8 phys-K ----------------
__global__ __launch_bounds__(256) void wconv(const float* __restrict__ Wz0,
                                             const float* __restrict__ Wf0,
                                             const float* __restrict__ Wo0,
                                             const float* __restrict__ Wz1,
                                             const float* __restrict__ Wf1,
                                             const float* __restrict__ Wo1,
                                             unsigned char* __restrict__ WT80,
                                             unsigned char* __restrict__ WT81) {
  __shared__ float tile[64][65];
  int z = blockIdx.z;
  int layer = z >= 6 ? 1 : 0, zz = z - 6 * layer;
  int g = zz >> 1, i = zz & 1;
  const float* src = layer == 0 ? (g == 0 ? Wz0 : (g == 1 ? Wf0 : Wo0))
                                : (g == 0 ? Wz1 : (g == 1 ? Wf1 : Wo1));
  unsigned char* WT8 = layer == 0 ? WT80 : WT81;
  src += (size_t)i * D * D;
  int d0 = blockIdx.x * 64, e0 = blockIdx.y * 64;
  int t = threadIdx.x, c = t & 63, rq = t >> 6;
#pragma unroll
  for (int p = 0; p < 16; ++p) {
    int dd = p * 4 + rq;
    tile[dd][c] = src[(size_t)(d0 + dd) * D + e0 + c];   // [k=d][n=e]
  }
  __syncthreads();
  tconv_write(tile, WT8 + (size_t)(g * D + e0) * 1024, 1024, i * 512 + d0, t);
}

// ---------------- softmax weight transpose+convert: fp8 (for tgl) + fp4 x32 (for lse) ----------------
__global__ __launch_bounds__(256) void swconv(const float* __restrict__ SW,
                                              unsigned char* __restrict__ SWT,
                                              unsigned char* __restrict__ SW4T) {
  __shared__ float tile[64][65];
  int k0 = blockIdx.x * 64, n0 = blockIdx.y * 64;
  int t = threadIdx.x, c = t & 63, rq = t >> 6;
#pragma unroll
  for (int p = 0; p < 16; ++p) {
    int kk = p * 4 + rq;
    tile[kk][c] = SW[(size_t)(k0 + kk) * V + n0 + c];
  }
  __syncthreads();
  tconv_write(tile, SWT + (size_t)n0 * 512, 512, k0, t);
  tconv4_write(tile, SW4T + (size_t)n0 * 256, 256, k0, t, 32.f);   // W x 2^5
}

// ---------------- H8 (fp8 phys-K) -> H4 (fp4 phys-K, x4 scale) repack ----------------
// phys byte i of H8 <-> phys nibble i of H4: pure elementwise.
__global__ __launch_bounds__(256) void h4pack(const unsigned char* __restrict__ H8,
                                              unsigned char* __restrict__ H4) {
  int i = blockIdx.x * 256 + threadIdx.x;       // over R*512/8 chunks
  uint2 v = *(const uint2*)(H8 + (size_t)i * 8);
  union { unsigned char c[4]; unsigned int q; } u;
#pragma unroll
  for (int b = 0; b < 4; ++b) {
    unsigned int w = (b < 2) ? v.x : v.y;
    int sh = (b & 1) * 16;
    unsigned char e0 = (w >> sh) & 255, e1 = (w >> (sh + 8)) & 255;
    u.c[b] = f2e2m1(e4m3f(e0) * 4.f) | (f2e2m1(e4m3f(e1) * 4.f) << 4);
  }
  *(unsigned int*)(H4 + (size_t)i * 4) = u.q;
}

// ---------------- MX-fp8 256x128 GEMM core (VERIFIED r14; used by gemm_pre) ----------------
template<int LD, int NKT>
__device__ __forceinline__ void mx_core256(const unsigned char* __restrict__ A,
                                           const unsigned char* __restrict__ B,
                                           int row0, int col0, char* lds,
                                           f32x4 acc[8][4]) {
  char* As = lds;            // 256 rows x 128B
  char* Bs = lds + 32768;    // 128 rows x 128B
  const int t = threadIdx.x, lane = t & 63, w = t >> 6;
  const int wm = w >> 1, wn = w & 1;
  const int lo = lane & 15, hi = lane >> 4;
  const int gr = t >> 3;             // row within 32-row issue
  const int ss = (t & 7) ^ (gr & 7); // inverse-swizzled source slot
  const int x  = lo & 7;             // frag-read row swizzle

#pragma unroll 1
  for (int kt = 0; kt < NKT; ++kt) {
    const int k0 = kt * 128;
#pragma unroll
    for (int i = 0; i < 8; ++i)
      gload16(A + (size_t)(row0 + i * 32 + gr) * LD + k0 + ss * 16,
              As + i * 4096 + t * 16);
#pragma unroll
    for (int i = 0; i < 4; ++i)
      gload16(B + (size_t)(col0 + i * 32 + gr) * LD + k0 + ss * 16,
              Bs + i * 4096 + t * 16);
    __syncthreads();
    i32x8 b8[4];
#pragma unroll
    for (int ni = 0; ni < 4; ++ni) {
      const char* rb = Bs + (wn * 64 + ni * 16 + lo) * 128;
      union { i32x8 v8; i32x4 v4[2]; } u;
      u.v4[0] = *(const i32x4*)(rb + ((hi * 2 + 0) ^ x) * 16);
      u.v4[1] = *(const i32x4*)(rb + ((hi * 2 + 1) ^ x) * 16);
      b8[ni] = u.v8;
    }
#pragma unroll
    for (int mi = 0; mi < 8; ++mi) {
      const char* rb = As + (wm * 128 + mi * 16 + lo) * 128;
      union { i32x8 v8; i32x4 v4[2]; } u;
      u.v4[0] = *(const i32x4*)(rb + ((hi * 2 + 0) ^ x) * 16);
      u.v4[1] = *(const i32x4*)(rb + ((hi * 2 + 1) ^ x) * 16);
      i32x8 a8 = u.v8;
#pragma unroll
      for (int ni = 0; ni < 4; ++ni)
        acc[mi][ni] = __builtin_amdgcn_mfma_scale_f32_16x16x128_f8f6f4(
            b8[ni], a8, acc[mi][ni], 0, 0, 0, 0x7F, 0, 0x7F);
    }
    __syncthreads();
  }
}

// ---------------- QRNN pre-activation GEMM (8192x1536x1024, MX-fp8, fused bias) ----------------
__global__ __launch_bounds__(256, 2) void gemm_pre_fp8(const unsigned char* __restrict__ A,
                                                       const unsigned char* __restrict__ B,
                                                       const float* __restrict__ bz,
                                                       const float* __restrict__ bf,
                                                       const float* __restrict__ bo,
                                                       ushort* __restrict__ PRE) {
  __shared__ char lds[49152];
  const int t = threadIdx.x, lane = t & 63, w = t >> 6;
  const int wm = w >> 1, wn = w & 1;
  const int lo = lane & 15, hi = lane >> 4;
  const int row0 = blockIdx.x * 256, col0 = blockIdx.y * 128;
  const int g = col0 >> 9;                       // gate uniform per block (128 | 512)
  const float* bg = (g == 0) ? bz : (g == 1 ? bf : bo);

  f32x4 acc[8][4];
#pragma unroll
  for (int i = 0; i < 8; ++i)
#pragma unroll
    for (int j = 0; j < 4; ++j) { f32x4 z = {0.f,0.f,0.f,0.f}; acc[i][j] = z; }

  mx_core256<1024, 8>(A, B, row0, col0, lds, acc);

#pragma unroll
  for (int mi = 0; mi < 8; ++mi) {
    const int row = row0 + wm * 128 + mi * 16 + lo;
#pragma unroll
    for (int ni = 0; ni < 4; ++ni) {
      const int colb = col0 + wn * 64 + ni * 16 + hi * 4;
      const int eb = colb & 511;
      ushort4 v;
      v.x = f2bf(acc[mi][ni][0] + bg[eb + 0]);
      v.y = f2bf(acc[mi][ni][1] + bg[eb + 1]);
      v.z = f2bf(acc[mi][ni][2] + bg[eb + 2]);
      v.w = f2bf(acc[mi][ni][3] + bg[eb + 3]);
      *(ushort4*)(PRE + (size_t)row * G3 + colb) = v;
    }
  }
}

// ---------------- target-logit kernel (+ SUM zero): fp8 path (unchanged) ----------------
__global__ __launch_bounds__(256) void tgl_kernel(const unsigned char* __restrict__ H8,
                                                  const unsigned char* __restrict__ SWT,
                                                  const float* __restrict__ SB,
                                                  const int* __restrict__ tgt,
                                                  float* __restrict__ TGL,
                                                  float* __restrict__ SUM) {
  int wid  = (blockIdx.x * 256 + threadIdx.x) >> 6;   // one wave per row
  int lane = threadIdx.x & 63;
  if (lane == 0) SUM[wid] = 0.f;                      // zero before lse's atomics
  int tg = tgt[wid];
  uint2 hv = *(const uint2*)(H8  + (size_t)wid * 512 + lane * 8);
  uint2 wv = *(const uint2*)(SWT + (size_t)tg  * 512 + lane * 8);
  float s = 0.f;
#pragma unroll
  for (int k = 0; k < 4; ++k)
    s += e4m3f((hv.x >> (8 * k)) & 255) * e4m3f((wv.x >> (8 * k)) & 255);
#pragma unroll
  for (int k = 0; k < 4; ++k)
    s += e4m3f((hv.y >> (8 * k)) & 255) * e4m3f((wv.y >> (8 * k)) & 255);
#pragma unroll
  for (int m = 1; m < 64; m <<= 1) s += __shfl_xor(s, m, 64);
  if (lane == 0) TGL[wid] = s + SB[tg];
}

// ---------------- MX-fp4 logits GEMM + fused exp-sum (256x128 tile) ----------------
// A4 [R][256B], B4 [V][256B]: fp4 phys-K (nibble i = physk elem i), A pre-scaled
// x4 (instr scale 2^-2 = 125), B x32 (2^-5 = 122). Row-per-kt = 64B = 4 slots;
// phys slot = (logical + swz(r)) & 3, swz(r) = ((r&3)+((r>>2)&3))&3 -> frag-read
// conflicts <= 2-way (free). One b128 per fragment. LDS 24KB -> high occupancy.
__global__ __launch_bounds__(256, 2) void gemm_lse_fp4(const unsigned char* __restrict__ A4,
                                                       const unsigned char* __restrict__ B4,
                                                       const float* __restrict__ SB,
                                                       float* __restrict__ SUM) {
  __shared__ char lds[24576];
  char* As = lds;            // 256 rows x 64B
  char* Bs = lds + 16384;    // 128 rows x 64B
  const int t = threadIdx.x, lane = t & 63, w = t >> 6;
  const int wm = w >> 1, wn = w & 1;
  const int lo = lane & 15, hi = lane >> 4;
  const int row0 = blockIdx.x * 256, col0 = blockIdx.y * 128;

  // staging geometry: issue covers 64 rows x 64B (256 thr x 16B); inverse swizzle
  const int gr = t >> 2;                                  // row within issue
  const int ls = ((t & 3) - ((gr & 3) + ((gr >> 2) & 3))) & 3;  // source logical slot

  float sb[16];
#pragma unroll
  for (int ni = 0; ni < 4; ++ni)
#pragma unroll
    for (int j = 0; j < 4; ++j)
      sb[ni * 4 + j] = SB[col0 + wn * 64 + ni * 16 + hi * 4 + j];

  f32x4 acc[8][4];
#pragma unroll
  for (int i = 0; i < 8; ++i)
#pragma unroll
    for (int j = 0; j < 4; ++j) { f32x4 z = {0.f,0.f,0.f,0.f}; acc[i][j] = z; }

#pragma unroll 1
  for (int kt = 0; kt < 4; ++kt) {
    const int k0b = kt * 64;                 // byte offset within 256B row
#pragma unroll
    for (int i = 0; i < 4; ++i)
      gload16(A4 + (size_t)(row0 + i * 64 + gr) * 256 + k0b + ls * 16,
              As + i * 4096 + t * 16);
#pragma unroll
    for (int i = 0; i < 2; ++i)
      gload16(B4 + (size_t)(col0 + i * 64 + gr) * 256 + k0b + ls * 16,
              Bs + i * 4096 + t * 16);
    __syncthreads();
    i32x8 b4[4];
#pragma unroll
    for (int ni = 0; ni < 4; ++ni) {
      int r = wn * 64 + ni * 16 + lo;
      int ps = (hi + (r & 3) + ((r >> 2) & 3)) & 3;
      union { i32x8 v8; i32x4 v4[2]; } u;
      u.v4[0] = *(const i32x4*)(Bs + r * 64 + ps * 16);
      i32x4 z4 = {0, 0, 0, 0};
      u.v4[1] = z4;
      b4[ni] = u.v8;
    }
#pragma unroll
    for (int mi = 0; mi < 8; ++mi) {
      int r = wm * 128 + mi * 16 + lo;
      int ps = (hi + (r & 3) + ((r >> 2) & 3)) & 3;
      union { i32x8 v8; i32x4 v4[2]; } u;
      u.v4[0] = *(const i32x4*)(As + r * 64 + ps * 16);
      i32x4 z4 = {0, 0, 0, 0};
      u.v4[1] = z4;
      i32x8 a4 = u.v8;
#pragma unroll
      for (int ni = 0; ni < 4; ++ni)
        acc[mi][ni] = __builtin_amdgcn_mfma_scale_f32_16x16x128_f8f6f4(
            b4[ni], a4, acc[mi][ni], 4, 4, 0, 122, 0, 125);  // fp4/fp4, 2^-5 / 2^-2
    }
    __syncthreads();
  }

  // epilogue (swapped layout): out_row = row0+wm*128+mi*16+lo (lane-local).
#pragma unroll
  for (int mi = 0; mi < 8; ++mi) {
    const int row = row0 + wm * 128 + mi * 16 + lo;
    float s0 = 0.f, s1 = 0.f, s2 = 0.f, s3 = 0.f;
#pragma unroll
    for (int ni = 0; ni < 4; ++ni) {
      s0 += __expf(acc[mi][ni][0] + sb[ni * 4 + 0]);
      s1 += __expf(acc[mi][ni][1] + sb[ni * 4 + 1]);
      s2 += __expf(acc[mi][ni][2] + sb[ni * 4 + 2]);
      s3 += __expf(acc[mi][ni][3] + sb[ni * 4 + 3]);
    }
    float s = (s0 + s1) + (s2 + s3);
    s += __shfl_xor(s, 16, 64);
    s += __shfl_xor(s, 32, 64);
    if (hi == 0) atomicAdd(&SUM[row], s);
  }
}

// ---------------- fused 4-segment parallel fo-pool scan (r15 exact) ----------------
__global__ __launch_bounds__(256) void scan_fused(const ushort* __restrict__ PRE,
                                                  unsigned char* __restrict__ OUT8,
                                                  int mode) {
  __shared__ float Als[4][64], Bls[4][64];
  const int b = blockIdx.x, dc = blockIdx.y;
  const int tid = threadIdx.x, dl = tid & 63, s = tid >> 6;   // s wave-uniform
  const int d = dc * 64 + dl;
  const ushort* p  = PRE + (size_t)b * TT * G3 + d;
  const ushort* ps = p + (size_t)(s * 64) * G3;

  float a = 1.f, c = 0.f;
  for (int t0 = 0; t0 < 64; t0 += 8) {
    float pz[8], pf[8];
#pragma unroll
    for (int i = 0; i < 8; ++i) {
      const ushort* q = ps + (size_t)(t0 + i) * G3;
      pz[i] = bf2f(q[0]); pf[i] = bf2f(q[512]);
    }
#pragma unroll
    for (int i = 0; i < 8; ++i) {
      float z = 2.f / (1.f + __expf(-2.f * pz[i])) - 1.f;
      float f = 1.f / (1.f + __expf(-pf[i]));
      c = f * c + (1.f - f) * z;
      a *= f;
    }
  }
  Als[s][dl] = a; Bls[s][dl] = c;
  __syncthreads();
  float cc = 0.f;
  for (int u = 0; u < s; ++u)          // wave-uniform bound, no divergence
    cc = Als[u][dl] * cc + Bls[u][dl];

  const int poff = physk(d);
  for (int t0 = s * 64; t0 < s * 64 + 64; t0 += 8) {
    float pz[8], pf[8], po[8];
#pragma unroll
    for (int i = 0; i < 8; ++i) {
      const ushort* q = p + (size_t)(t0 + i) * G3;
      pz[i] = bf2f(q[0]); pf[i] = bf2f(q[512]); po[i] = bf2f(q[1024]);
    }
#pragma unroll
    for (int i = 0; i < 8; ++i) {
      float z = 2.f / (1.f + __expf(-2.f * pz[i])) - 1.f;
      float f = 1.f / (1.f + __expf(-pf[i]));
      float o = 1.f / (1.f + __expf(-po[i]));
      cc = f * cc + (1.f - f) * z;
      float h = o * cc;
      int tt = t0 + i;
      size_t r = (size_t)b * TT + tt;
      unsigned char hb = f2e4m3(h);
      if (mode == 0) {
        OUT8[r * 1024 + 512 + poff] = hb;
        if (tt < TT - 1) OUT8[(r + 1) * 1024 + poff] = hb;
        if (tt == 0)     OUT8[r * 1024 + poff] = 0;
      } else {
        OUT8[r * 512 + poff] = hb;
      }
    }
  }
}

// ---------------- final cost ----------------
__global__ __launch_bounds__(256) void cost_kernel(const float* __restrict__ sumexp,
                                                   const float* __restrict__ tgl,
                                                   float* __restrict__ out) {
  int t = threadIdx.x;
  float s = 0.f;
  for (int r = t; r < R; r += 256) s += logf(sumexp[r]) - tgl[r];
#pragma unroll
  for (int m = 1; m < 64; m <<= 1) s += __shfl_xor(s, m, 64);
  __shared__ float red[4];
  int wave = t >> 6, lane = t & 63;
  if (lane == 0) red[wave] = s;
  __syncthreads();
  if (t == 0) out[0] = (red[0] + red[1] + red[2] + red[3]) / (float)R;
}

extern "C" void kernel_launch(void* const* d_in, const int* in_sizes, int n_in,
                              void* d_out, int out_size, void* d_ws, size_t ws_size,
                              hipStream_t stream) {
  const int*   tok = (const int*)d_in[0];
  const int*   tgt = (const int*)d_in[1];
  const float* emb = (const float*)d_in[2];
  const float* Wz0 = (const float*)d_in[3];  const float* bz0 = (const float*)d_in[4];
  const float* Wf0 = (const float*)d_in[5];  const float* bf0 = (const float*)d_in[6];
  const float* Wo0 = (const float*)d_in[7];  const float* bo0 = (const float*)d_in[8];
  const float* Wz1 = (const float*)d_in[9];  const float* bz1 = (const float*)d_in[10];
  const float* Wf1 = (const float*)d_in[11]; const float* bf1 = (const float*)d_in[12];
  const float* Wo1 = (const float*)d_in[13]; const float* bo1 = (const float*)d_in[14];
  const float* SW  = (const float*)d_in[15]; const float* SB  = (const float*)d_in[16];
  float* out = (float*)d_out;

  // workspace layout (bytes), total ~59.6 MB:
  char* base = (char*)d_ws;
  unsigned char* XA8  = (unsigned char*)(base);             //  8,388,608 [R][1024] fp8 phys-K
  unsigned char* YA8  = (unsigned char*)(base + 8388608);   //  8,388,608
  ushort*        PRE  = (ushort*)(base + 16777216);         // 25,165,824 [R][1536] bf16
  unsigned char* H8   = (unsigned char*)(base + 41943040);  //  4,194,304 [R][512] fp8 phys-K
  unsigned char* WT80 = (unsigned char*)(base + 46137344);  //  1,572,864
  unsigned char* WT81 = (unsigned char*)(base + 47710208);  //  1,572,864
  float*         SUM  = (float*)(base + 49283072);          //  32,768
  float*         TGL  = (float*)(base + 49315840);          //  32,768
  unsigned char* H4   = (unsigned char*)(base + 49348608);  //  2,097,152 [R][256] fp4 phys-K
  unsigned char* SW4T = (unsigned char*)(base + 51445760);  //  8,192,000 [V][256] fp4 phys-K
  unsigned char* SW8T = (unsigned char*)(base);             // 16,384,000 — aliases XA8+YA8 (dead by then)

  embed_kernel<<<R * 128 / 256, 256, 0, stream>>>(tok, (const float4*)emb, XA8);
  wconv<<<dim3(8, 8, 12), 256, 0, stream>>>(Wz0, Wf0, Wo0, Wz1, Wf1, Wo1, WT80, WT81);

  gemm_pre_fp8<<<dim3(32, 12), 256, 0, stream>>>(XA8, WT80, bz0, bf0, bo0, PRE);
  scan_fused<<<dim3(32, 8), 256, 0, stream>>>(PRE, YA8, 0);
  gemm_pre_fp8<<<dim3(32, 12), 256, 0, stream>>>(YA8, WT81, bz1, bf1, bo1, PRE);
  scan_fused<<<dim3(32, 8), 256, 0, stream>>>(PRE, H8, 1);

  // SW8T aliases XA8/YA8 — both dead after the second gemm_pre_fp8
  swconv<<<dim3(8, 500), 256, 0, stream>>>(SW, SW8T, SW4T);
  h4pack<<<R * 512 / 8 / 256, 256, 0, stream>>>(H8, H4);
  tgl_kernel<<<R / 4, 256, 0, stream>>>(H8, SW8T, SB, tgt, TGL, SUM);
  gemm_lse_fp4<<<dim3(32, 250), 256, 0, stream>>>(H4, SW4T, SB, SUM);
  cost_kernel<<<1, 256, 0, stream>>>(SUM, TGL, out);
}